// Round 9
// baseline (497.129 us; speedup 1.0000x reference)
//
#include <hip/hip_runtime.h>
#include <hip/hip_bf16.h>

// Problem constants
#define PB 4
#define PN 2048
#define PD 1024
#define PH 16
#define PHD 64
#define NSC 11

typedef __attribute__((ext_vector_type(8))) short short8;
typedef __attribute__((ext_vector_type(4))) float floatx4;

#define AS1 __attribute__((address_space(1)))
#define AS3 __attribute__((address_space(3)))

static __device__ __forceinline__ unsigned short bf16bits(float f) {
    __hip_bfloat16 h = __float2bfloat16(f);
    return __builtin_bit_cast(unsigned short, h);
}

// ---------------- merged cast kernel (one launch) ----------------
// x (8M floats) -> x_bf ; W_qkv(3M)+W_gate(1M) -> wcomb ; W_out(1M) -> woutb
__global__ void cast_all(const float4* __restrict__ x,
                         const float4* __restrict__ wqkv,
                         const float4* __restrict__ wgate,
                         const float4* __restrict__ wout,
                         ushort4* __restrict__ x_bf,
                         ushort4* __restrict__ wcomb,
                         ushort4* __restrict__ woutb) {
    int i = blockIdx.x * blockDim.x + threadIdx.x;
    const int X4 = PB * PN * PD / 4;
    const int QKV4 = 3 * PD * PD / 4;
    const int G4 = PD * PD / 4;
    float4 v;
    ushort4* dst;
    if (i < X4) {
        v = x[i];
        dst = x_bf + i;
    } else {
        int j = i - X4;
        if (j < QKV4) {
            v = wqkv[j];
            dst = wcomb + j;
        } else if (j < QKV4 + G4) {
            v = wgate[j - QKV4];
            dst = wcomb + j;
        } else {
            v = wout[j - QKV4 - G4];
            dst = woutb + (j - QKV4 - G4);
        }
    }
    ushort4 o;
    o.x = bf16bits(v.x);
    o.y = bf16bits(v.y);
    o.z = bf16bits(v.z);
    o.w = bf16bits(v.w);
    *dst = o;
}

// ---------------- GEMM 128x128 (kept for gemm2: N=1024 -> 512 blocks) -------
#define GBM 128
#define GBN 128
#define GBK 64

__global__ __launch_bounds__(256) void gemm_bt128(
    const __hip_bfloat16* __restrict__ A,
    const __hip_bfloat16* __restrict__ Bm,
    const float* __restrict__ b1,
    const float* __restrict__ b2,
    int split,
    float* __restrict__ out1, int N1,
    float* __restrict__ out2, int N2,
    int K) {
    __shared__ alignas(16) __hip_bfloat16 sA[GBM * GBK];
    __shared__ alignas(16) __hip_bfloat16 sB[GBN * GBK];

    const int tid = threadIdx.x;
    const int lane = tid & 63;
    const int wave = tid >> 6;   // 0..3
    const int wy = wave >> 1;    // 0..1
    const int wx = wave & 1;     // 0..1

    const int lrow8 = lane >> 3;                 // 0..7
    const int lchunk = lane & 7;                 // LDS chunk slot (8 elems)
    const int gchunk = lchunk ^ lrow8;           // global chunk fetched into slot

    const int r16 = lane & 15;
    const int qd = lane >> 4;
    const int sw = r16 & 7;  // reader swizzle key

    floatx4 acc[4][4];
#pragma unroll
    for (int i = 0; i < 4; i++)
#pragma unroll
        for (int j = 0; j < 4; j++) acc[i][j] = (floatx4){0.f, 0.f, 0.f, 0.f};

    const size_t arow0 = (size_t)blockIdx.y * GBM;
    const size_t brow0 = (size_t)blockIdx.x * GBN;

    for (int k0 = 0; k0 < K; k0 += GBK) {
        __syncthreads();  // previous ds_reads done before overwrite
#pragma unroll
        for (int half = 0; half < 4; half++) {
            const int rbase = wave * 8 + half * 32;  // wave-uniform
            const __hip_bfloat16* gA =
                A + (arow0 + rbase + lrow8) * K + k0 + gchunk * 8;
            __builtin_amdgcn_global_load_lds(
                (const AS1 unsigned int*)(const void*)gA,
                (AS3 unsigned int*)(void*)(sA + rbase * GBK), 16, 0, 0);
            const __hip_bfloat16* gB =
                Bm + (brow0 + rbase + lrow8) * K + k0 + gchunk * 8;
            __builtin_amdgcn_global_load_lds(
                (const AS1 unsigned int*)(const void*)gB,
                (AS3 unsigned int*)(void*)(sB + rbase * GBK), 16, 0, 0);
        }
        __syncthreads();  // drain staging

#pragma unroll
        for (int kk = 0; kk < 2; kk++) {
            short8 af[4], bf[4];
            const int cs = (qd + 4 * kk);
#pragma unroll
            for (int i = 0; i < 4; i++)
                af[i] = *(const short8*)(sA + (wy * 64 + i * 16 + r16) * GBK +
                                         ((cs ^ sw) * 8));
#pragma unroll
            for (int j = 0; j < 4; j++)
                bf[j] = *(const short8*)(sB + (wx * 64 + j * 16 + r16) * GBK +
                                         ((cs ^ sw) * 8));
#pragma unroll
            for (int i = 0; i < 4; i++)
#pragma unroll
                for (int j = 0; j < 4; j++)
                    acc[i][j] = __builtin_amdgcn_mfma_f32_16x16x32_bf16(
                        af[i], bf[j], acc[i][j], 0, 0, 0);
        }
    }

#pragma unroll
    for (int i = 0; i < 4; i++) {
#pragma unroll
        for (int j = 0; j < 4; j++) {
            const int colb = (int)brow0 + wx * 64 + j * 16 + r16;
            const bool first = colb < split;
            const float bb = first ? b1[colb] : b2[colb - split];
            float* dst = first ? out1 : out2;
            const int nn = first ? N1 : N2;
            const int cc = first ? colb : colb - split;
#pragma unroll
            for (int e = 0; e < 4; e++) {
                const size_t row = arow0 + wy * 64 + i * 16 + qd * 4 + e;
                dst[row * (size_t)nn + cc] = acc[i][j][e] + bb;
            }
        }
    }
}

// ---------------- GEMM 256x256, 8 waves, counted-vmcnt schedule (gemm1) ----
// R5 structure (proven ~90 us / 760 TF). R6's finer 4-phase barrier graft
// REGRESSED (111 us) — keep R5 verbatim.
#define TBM 256
#define TBN 256
#define TBK 64

__global__ __launch_bounds__(512) void gemm_bt256(
    const __hip_bfloat16* __restrict__ A,
    const __hip_bfloat16* __restrict__ Bm,
    const float* __restrict__ b1,
    const float* __restrict__ b2,
    int split,
    float* __restrict__ out1, int N1,
    float* __restrict__ out2, int N2,
    int K) {
    __shared__ alignas(16) __hip_bfloat16 sA[2 * TBM * TBK];  // 64 KiB
    __shared__ alignas(16) __hip_bfloat16 sB[2 * TBN * TBK];  // 64 KiB

    const int tid = threadIdx.x;
    const int lane = tid & 63;
    const int wid = tid >> 6;    // 0..7
    const int wrow = wid >> 2;   // 0..1 : M half (128 rows)
    const int wcol = wid & 3;    // 0..3 : N quarter (64 cols)

    const int lrow8 = lane >> 3;
    const int lchunk = lane & 7;
    const int gchunk = lchunk ^ lrow8;  // write-side chunk swizzle

    const int r16 = lane & 15;
    const int qd = lane >> 4;
    const int sw = r16 & 7;  // read-side swizzle key

    const size_t arow0 = (size_t)blockIdx.y * TBM;
    const size_t brow0 = (size_t)blockIdx.x * TBN;

    const int nt = K >> 6;  // K-tiles
    const size_t rowskip = (size_t)64 * K;

    const __hip_bfloat16* gA = A + (arow0 + wid * 8 + lrow8) * (size_t)K + gchunk * 8;
    const __hip_bfloat16* gB = Bm + (brow0 + wid * 8 + lrow8) * (size_t)K + gchunk * 8;
    const int ldsAb = wid * 8 * TBK;  // wave-uniform LDS base (elems)

    auto stage = [&](int cc, int ktn) {
#pragma unroll
        for (int rd = 0; rd < 4; ++rd) {
            __builtin_amdgcn_global_load_lds(
                (const AS1 unsigned int*)(const void*)(gA + (size_t)rd * rowskip + ktn * TBK),
                (AS3 unsigned int*)(void*)(sA + cc * (TBM * TBK) + ldsAb + rd * (64 * TBK)),
                16, 0, 0);
            __builtin_amdgcn_global_load_lds(
                (const AS1 unsigned int*)(const void*)(gB + (size_t)rd * rowskip + ktn * TBK),
                (AS3 unsigned int*)(void*)(sB + cc * (TBN * TBK) + ldsAb + rd * (64 * TBK)),
                16, 0, 0);
        }
    };

    floatx4 acc[8][4];
#pragma unroll
    for (int i = 0; i < 8; i++)
#pragma unroll
        for (int j = 0; j < 4; j++) acc[i][j] = (floatx4){0.f, 0.f, 0.f, 0.f};

    const int aofs = (wrow * 128 + r16) * TBK;
    const int bofs = (wcol * 64 + r16) * TBK;
    const int ck0 = ((qd ^ sw) * 8);
    const int ck1 = (((qd + 4) ^ sw) * 8);

    // prologue: stage K-tiles 0 and 1
    stage(0, 0);
    stage(1, 1);
    asm volatile("s_waitcnt vmcnt(8)" ::: "memory");  // K-tile 0 landed
    __builtin_amdgcn_s_barrier();

#pragma unroll 1
    for (int kt = 0; kt < nt; ++kt) {
        const int c = kt & 1;
        const __hip_bfloat16* sAc = sA + c * (TBM * TBK);
        const __hip_bfloat16* sBc = sB + c * (TBN * TBK);

        short8 afr[8][2], bfr[4][2];

        // ---- Phase A: ds_read af rh0 (rf0-3) + bf ch0 (cf0-1); MFMA Q0
#pragma unroll
        for (int f = 0; f < 2; ++f) {
            bfr[f][0] = *(const short8*)(sBc + bofs + f * 1024 + ck0);
            bfr[f][1] = *(const short8*)(sBc + bofs + f * 1024 + ck1);
        }
#pragma unroll
        for (int f = 0; f < 4; ++f) {
            afr[f][0] = *(const short8*)(sAc + aofs + f * 1024 + ck0);
            afr[f][1] = *(const short8*)(sAc + aofs + f * 1024 + ck1);
        }
        __builtin_amdgcn_s_setprio(1);
#pragma unroll
        for (int i = 0; i < 4; ++i)
#pragma unroll
            for (int j = 0; j < 2; ++j)
#pragma unroll
                for (int kk = 0; kk < 2; ++kk)
                    acc[i][j] = __builtin_amdgcn_mfma_f32_16x16x32_bf16(
                        afr[i][kk], bfr[j][kk], acc[i][j], 0, 0, 0);
        __builtin_amdgcn_s_setprio(0);

        // ---- Phase B: ds_read bf ch1 (cf2-3) + af rh1 (rf4-7); MFMA Q1
#pragma unroll
        for (int f = 2; f < 4; ++f) {
            bfr[f][0] = *(const short8*)(sBc + bofs + f * 1024 + ck0);
            bfr[f][1] = *(const short8*)(sBc + bofs + f * 1024 + ck1);
        }
#pragma unroll
        for (int f = 4; f < 8; ++f) {
            afr[f][0] = *(const short8*)(sAc + aofs + f * 1024 + ck0);
            afr[f][1] = *(const short8*)(sAc + aofs + f * 1024 + ck1);
        }
        __builtin_amdgcn_s_setprio(1);
#pragma unroll
        for (int i = 0; i < 4; ++i)
#pragma unroll
            for (int j = 2; j < 4; ++j)
#pragma unroll
            for (int kk = 0; kk < 2; ++kk)
                    acc[i][j] = __builtin_amdgcn_mfma_f32_16x16x32_bf16(
                        afr[i][kk], bfr[j][kk], acc[i][j], 0, 0, 0);
        __builtin_amdgcn_s_setprio(0);

        // ---- boundary 1: all reads of buf[c] complete across the block
        asm volatile("s_waitcnt lgkmcnt(0)" ::: "memory");
        __builtin_amdgcn_sched_barrier(0);
        __builtin_amdgcn_s_barrier();

        // stage kt+2 into buf[c] (now safe to overwrite)
        if (kt + 2 < nt) stage(c, kt + 2);

        // ---- Phase C: pure-register MFMA Q2 (rf4-7 x cf0-1)
        __builtin_amdgcn_s_setprio(1);
#pragma unroll
        for (int i = 4; i < 8; ++i)
#pragma unroll
            for (int j = 0; j < 2; ++j)
#pragma unroll
                for (int kk = 0; kk < 2; ++kk)
                    acc[i][j] = __builtin_amdgcn_mfma_f32_16x16x32_bf16(
                        afr[i][kk], bfr[j][kk], acc[i][j], 0, 0, 0);
        __builtin_amdgcn_s_setprio(0);

        // ---- Phase D: pure-register MFMA Q3 (rf4-7 x cf2-3)
        __builtin_amdgcn_s_setprio(1);
#pragma unroll
        for (int i = 4; i < 8; ++i)
#pragma unroll
            for (int j = 2; j < 4; ++j)
#pragma unroll
                for (int kk = 0; kk < 2; ++kk)
                    acc[i][j] = __builtin_amdgcn_mfma_f32_16x16x32_bf16(
                        afr[i][kk], bfr[j][kk], acc[i][j], 0, 0, 0);
        __builtin_amdgcn_s_setprio(0);

        // ---- boundary 2: kt+1's data landed; kt+2's loads stay in flight
        if (kt + 2 < nt) {
            asm volatile("s_waitcnt vmcnt(8)" ::: "memory");
        } else if (kt + 1 < nt) {
            asm volatile("s_waitcnt vmcnt(0)" ::: "memory");
        }
        if (kt + 1 < nt) __builtin_amdgcn_s_barrier();
    }

    // ---- epilogue (same proven C/D mapping, dual output + bias)
#pragma unroll
    for (int i = 0; i < 8; i++) {
#pragma unroll
        for (int j = 0; j < 4; j++) {
            const int colb = (int)brow0 + wcol * 64 + j * 16 + r16;
            const bool first = colb < split;
            const float bb = first ? b1[colb] : b2[colb - split];
            float* dst = first ? out1 : out2;
            const int nn = first ? N1 : N2;
            const int cc = first ? colb : colb - split;
#pragma unroll
            for (int e = 0; e < 4; e++) {
                const size_t row = arow0 + wrow * 128 + i * 16 + qd * 4 + e;
                dst[row * (size_t)nn + cc] = acc[i][j][e] + bb;
            }
        }
    }
}

// ---------------- attention kernel (8 lanes / position, float8 per lane) ----
// R4: XCD-chunked swizzle (k/v L2 locality). R7: gate fused, bf16 out (proven
// 88 VGPR / 90 us). R8 lesson: f32x2 packed rewrite + hoisted gate loads blew
// VGPR to 148 (occupancy 11%, 116 us) — body reverted to R7 exactly.
// R9 experiment: __launch_bounds__(256, 6) asks the allocator for <=85 VGPR
// (6 waves/SIMD vs 5 at 88). Only -3 regs vs natural — mild, unlike R2's
// catastrophic -26. Spill tripwire: WRITE_SIZE must stay 16384 KB.

static constexpr int OFFS[21] = {1, 2, 3, 4, 6, 8, 12, 16, 24, 32, 48,
                                 64, 96, 128, 192, 256, 384, 512, 768, 1024, 1536};
static constexpr int U1J[21] = {0, 0, 0, 1, 1, 2, 2, 3, 3, 4, 4,
                                5, 5, 6, 6, 7, 7, 8, 8, 9, 9};
static constexpr int U1T[21] = {1, 2, 3, 2, 3, 2, 3, 2, 3, 2, 3,
                                2, 3, 2, 3, 2, 3, 2, 3, 2, 3};
// second user j (tau is always 1); -1 = none
static constexpr int U2J[21] = {-1, 1, -1, 2, -1, 3, -1, 4, -1, 5, -1,
                                6, -1, 7, -1, 8, -1, 9, -1, 10, -1};

static __device__ __forceinline__ float red8(float s) {
    // sum across each 8-lane group; all 8 lanes get the sum.
    int t;
    // quad_perm [1,0,3,2] : lane ^ 1
    t = __builtin_amdgcn_update_dpp(0, __builtin_bit_cast(int, s), 0xB1, 0xF, 0xF, true);
    s += __builtin_bit_cast(float, t);
    // quad_perm [2,3,0,1] : lane ^ 2
    t = __builtin_amdgcn_update_dpp(0, __builtin_bit_cast(int, s), 0x4E, 0xF, 0xF, true);
    s += __builtin_bit_cast(float, t);
    // row_half_mirror : lane i <-> 7-i (within 8-lane half-row)
    t = __builtin_amdgcn_update_dpp(0, __builtin_bit_cast(int, s), 0x141, 0xF, 0xF, true);
    s += __builtin_bit_cast(float, t);
    return s;
}

__global__ __launch_bounds__(256, 6) void attn_kernel(
    const float* __restrict__ qkv,
    const float* __restrict__ scale_gain,       // [11,16]
    const float* __restrict__ W_qscale,         // [11,64]
    const float* __restrict__ identity_bypass,  // [16]
    const float* __restrict__ pos_bias,         // [44,16]
    const float* __restrict__ gate,             // [8192,1024] fp32 (pre-sigmoid)
    __hip_bfloat16* __restrict__ gated) {       // [8192,1024] bf16 out
    const int lane = threadIdx.x & 63;
    const int p = lane >> 3;   // position within wave, 0..7
    const int l = lane & 7;    // d-chunk (8 floats), 0..7

    // XCD-chunked swizzle: hw assigns block i -> XCD i%8; give XCD x the
    // contiguous strip range [x*512, (x+1)*512). 4096 % 8 == 0 -> bijective.
    const int wg = blockIdx.x;
    const int swg = (wg & 7) * 512 + (wg >> 3);

    const int flat = (swg * 4 + (threadIdx.x >> 6)) * 8;  // first n of wave
    const int n = (flat & (PN - 1)) + p;
    const int h = (flat >> 11) & (PH - 1);
    const int b = flat >> 15;

    const size_t base_bn = (size_t)b * PN;
    const int col = h * PHD + l * 8;

    const float* qp = qkv + (base_bn + n) * (3 * PD) + col;
    const float4 qa = *(const float4*)qp;
    const float4 qb = *(const float4*)(qp + 4);
    const float4 k0a = *(const float4*)(qp + PD);
    const float4 k0b = *(const float4*)(qp + PD + 4);
    const float4 v0a = *(const float4*)(qp + 2 * PD);
    const float4 v0b = *(const float4*)(qp + 2 * PD + 4);

    auto dot8 = [](float4 a0, float4 a1, float4 b0, float4 b1) {
        float s = a0.x * b0.x;
        s = fmaf(a0.y, b0.y, s);
        s = fmaf(a0.z, b0.z, s);
        s = fmaf(a0.w, b0.w, s);
        s = fmaf(a1.x, b1.x, s);
        s = fmaf(a1.y, b1.y, s);
        s = fmaf(a1.z, b1.z, s);
        s = fmaf(a1.w, b1.w, s);
        return red8(s);
    };

    const float dot0 = dot8(qa, qb, k0a, k0b);  // k0 regs die here

    // gains = softmax(q @ W_qscale^T + scale_gain[:,h]) over 11 scales
    float g[NSC];
    float mx = -1e30f;
#pragma unroll
    for (int s = 0; s < NSC; s++) {
        const float* wp = W_qscale + s * PHD + l * 8;
        const float4 w0 = *(const float4*)wp;
        const float4 w1 = *(const float4*)(wp + 4);
        g[s] = dot8(qa, qb, w0, w1) + scale_gain[s * PH + h];
        mx = fmaxf(mx, g[s]);
    }
    float ssum = 0.f;
#pragma unroll
    for (int s = 0; s < NSC; s++) {
        g[s] = __expf(g[s] - mx);
        ssum += g[s];
    }
    const float inv = 1.f / ssum;
#pragma unroll
    for (int s = 0; s < NSC; s++) g[s] *= inv;

    const float D4c[4] = {0.4829629131445341f, 0.8365163037378079f,
                          0.2241438680420134f, -0.1294095225512604f};

    float4 o0, o1;
    float z;

    // ---- offset-0 block: 11 tau=0 taps + identity bypass, all scale v0.
    {
        const float bp = log1pf(__expf(identity_bypass[h]));  // softplus
        const float f0 = (dot0 > 0.f ? dot0 : __expf(dot0) - 1.f) + 1.f;
        float wsum = bp * f0;
#pragma unroll
        for (int j = 0; j < NSC; j++) {
            const float xx = dot0 + pos_bias[(j * 4) * PH + h];
            const float feat = (xx > 0.f ? xx : __expf(xx) - 1.f) + 1.f;
            wsum = fmaf(g[j], D4c[0] * feat, wsum);
        }
        z = wsum;
        o0.x = wsum * v0a.x;
        o0.y = wsum * v0a.y;
        o0.z = wsum * v0a.z;
        o0.w = wsum * v0a.w;
        o1.x = wsum * v0b.x;
        o1.y = wsum * v0b.y;
        o1.z = wsum * v0b.z;
        o1.w = wsum * v0b.w;
    }  // v0 regs die here

    // ---- distinct nonzero offsets (each used by 1-2 taps, sharing k/v rows)
#pragma unroll
    for (int t = 0; t < 21; t++) {
        const int off = OFFS[t];
        const bool valid = (n >= off);
        const int idx = valid ? (n - off) : 0;
        const float vm = valid ? 1.f : 0.f;
        const size_t rb = (base_bn + idx) * (3 * PD);
        const float* kp = qkv + rb + PD + col;
        const float* vp = qkv + rb + 2 * PD + col;
        const float4 k4a = *(const float4*)kp;
        const float4 k4b = *(const float4*)(kp + 4);
        const float4 v4a = *(const float4*)vp;
        const float4 v4b = *(const float4*)(vp + 4);
        const float dv = dot8(qa, qb, k4a, k4b) * vm;

        // user 1: (U1J[t], U1T[t])
        float wv, zacc;
        {
            const int j = U1J[t], tau = U1T[t];
            const float xx = dv + pos_bias[(j * 4 + tau) * PH + h];
            const float feat = (xx > 0.f ? xx : __expf(xx) - 1.f) + 1.f;
            const float wp = g[j] * (D4c[tau] * feat);
            zacc = fabsf(wp);  // = g * |coef| * feat  (g,feat >= 0)
            wv = wp;
        }
        // user 2: (U2J[t], tau=1) if present
        if (U2J[t] >= 0) {
            const int j = U2J[t];
            const float xx = dv + pos_bias[(j * 4 + 1) * PH + h];
            const float feat = (xx > 0.f ? xx : __expf(xx) - 1.f) + 1.f;
            const float wp = g[j] * (D4c[1] * feat);
            zacc += wp;  // coef > 0
            wv += wp;
        }
        z += zacc;
        wv *= vm;
        o0.x = fmaf(wv, v4a.x, o0.x);
        o0.y = fmaf(wv, v4a.y, o0.y);
        o0.z = fmaf(wv, v4a.z, o0.z);
        o0.w = fmaf(wv, v4a.w, o0.w);
        o1.x = fmaf(wv, v4b.x, o1.x);
        o1.y = fmaf(wv, v4b.y, o1.y);
        o1.z = fmaf(wv, v4b.z, o1.z);
        o1.w = fmaf(wv, v4b.w, o1.w);
    }

    // ---- tail: normalize, gate (sigmoid), emit bf16
    const float* gp2 = gate + (base_bn + n) * PD + col;
    const float4 ga = *(const float4*)gp2;
    const float4 gb = *(const float4*)(gp2 + 4);
    const float zi = 1.f / (z + 1e-6f);

    short8 r;
    r[0] = (short)bf16bits(o0.x * zi / (1.f + __expf(-ga.x)));
    r[1] = (short)bf16bits(o0.y * zi / (1.f + __expf(-ga.y)));
    r[2] = (short)bf16bits(o0.z * zi / (1.f + __expf(-ga.z)));
    r[3] = (short)bf16bits(o0.w * zi / (1.f + __expf(-ga.w)));
    r[4] = (short)bf16bits(o1.x * zi / (1.f + __expf(-gb.x)));
    r[5] = (short)bf16bits(o1.y * zi / (1.f + __expf(-gb.y)));
    r[6] = (short)bf16bits(o1.z * zi / (1.f + __expf(-gb.z)));
    r[7] = (short)bf16bits(o1.w * zi / (1.f + __expf(-gb.w)));
    *(short8*)(gated + (base_bn + n) * PD + col) = r;
}

// ---------------- launch ----------------
extern "C" void kernel_launch(void* const* d_in, const int* in_sizes, int n_in,
                              void* d_out, int out_size, void* d_ws, size_t ws_size,
                              hipStream_t stream) {
    const float* x = (const float*)d_in[0];
    const float* W_qkv = (const float*)d_in[1];
    const float* b_qkv = (const float*)d_in[2];
    const float* W_out = (const float*)d_in[3];
    const float* b_out = (const float*)d_in[4];
    const float* W_gate = (const float*)d_in[5];
    const float* b_gate = (const float*)d_in[6];
    const float* scale_gain = (const float*)d_in[7];
    const float* W_qscale = (const float*)d_in[8];
    const float* identity_bypass = (const float*)d_in[9];
    const float* pos_bias = (const float*)d_in[10];
    float* out = (float*)d_out;

    const int M = PB * PN;  // 8192
    char* ws = (char*)d_ws;
    size_t off = 0;
    auto alloc = [&](size_t bytes) -> void* {
        void* p = ws + off;
        off += (bytes + 255) & ~(size_t)255;
        return p;
    };
    __hip_bfloat16* x_bf = (__hip_bfloat16*)alloc((size_t)M * PD * 2);
    __hip_bfloat16* wcomb_bf = (__hip_bfloat16*)alloc((size_t)4 * PD * PD * 2);
    __hip_bfloat16* wout_bf = (__hip_bfloat16*)alloc((size_t)PD * PD * 2);
    float* qkv = (float*)alloc((size_t)M * 3 * PD * 4);
    float* gate = (float*)alloc((size_t)M * PD * 4);
    __hip_bfloat16* gated = (__hip_bfloat16*)alloc((size_t)M * PD * 2);

    // merged casts: x -> bf16, weights -> bf16 (one dispatch)
    const int TOT4 = M * PD / 4 + 5 * PD * PD / 4;
    cast_all<<<TOT4 / 256, 256, 0, stream>>>(
        (const float4*)x, (const float4*)W_qkv, (const float4*)W_gate,
        (const float4*)W_out, (ushort4*)x_bf, (ushort4*)wcomb_bf,
        (ushort4*)wout_bf);

    // {qkv, gate} = x @ [W_qkv; W_gate]^T + {b_qkv, b_gate}  (256² pipeline)
    gemm_bt256<<<dim3(4 * PD / TBN, M / TBM), 512, 0, stream>>>(
        x_bf, wcomb_bf, b_qkv, b_gate, 3 * PD, qkv, 3 * PD, gate, PD, PD);

    // attention + gate + bf16 emit -> gated [8192,1024] bf16
    attn_kernel<<<(PB * PH * PN) / 32, 256, 0, stream>>>(
        qkv, scale_gain, W_qscale, identity_bypass, pos_bias, gate, gated);

    // out = gated @ W_out^T + b_out  -> fp32  (N=1024 -> keep 128² for 512 blocks)
    gemm_bt128<<<dim3(PD / GBN, M / GBM), 256, 0, stream>>>(
        gated, wout_bf, b_out, b_out, PD, out, PD, out, PD, PD);
}

// Round 10
// 292.444 us; speedup vs baseline: 1.6999x; 1.6999x over previous
//
#include <hip/hip_runtime.h>
#include <hip/hip_bf16.h>

// Problem constants
#define PB 4
#define PN 2048
#define PD 1024
#define PH 16
#define PHD 64
#define NSC 11

typedef __attribute__((ext_vector_type(8))) short short8;
typedef __attribute__((ext_vector_type(4))) float floatx4;

#define AS1 __attribute__((address_space(1)))
#define AS3 __attribute__((address_space(3)))

static __device__ __forceinline__ unsigned short bf16bits(float f) {
    __hip_bfloat16 h = __float2bfloat16(f);
    return __builtin_bit_cast(unsigned short, h);
}

// ---------------- merged cast kernel (one launch) ----------------
// x (8M floats) -> x_bf ; W_qkv(3M)+W_gate(1M) -> wcomb ; W_out(1M) -> woutb
__global__ void cast_all(const float4* __restrict__ x,
                         const float4* __restrict__ wqkv,
                         const float4* __restrict__ wgate,
                         const float4* __restrict__ wout,
                         ushort4* __restrict__ x_bf,
                         ushort4* __restrict__ wcomb,
                         ushort4* __restrict__ woutb) {
    int i = blockIdx.x * blockDim.x + threadIdx.x;
    const int X4 = PB * PN * PD / 4;
    const int QKV4 = 3 * PD * PD / 4;
    const int G4 = PD * PD / 4;
    float4 v;
    ushort4* dst;
    if (i < X4) {
        v = x[i];
        dst = x_bf + i;
    } else {
        int j = i - X4;
        if (j < QKV4) {
            v = wqkv[j];
            dst = wcomb + j;
        } else if (j < QKV4 + G4) {
            v = wgate[j - QKV4];
            dst = wcomb + j;
        } else {
            v = wout[j - QKV4 - G4];
            dst = woutb + (j - QKV4 - G4);
        }
    }
    ushort4 o;
    o.x = bf16bits(v.x);
    o.y = bf16bits(v.y);
    o.z = bf16bits(v.z);
    o.w = bf16bits(v.w);
    *dst = o;
}

// ---------------- GEMM 128x128 (kept for gemm2: N=1024 -> 512 blocks) -------
#define GBM 128
#define GBN 128
#define GBK 64

__global__ __launch_bounds__(256) void gemm_bt128(
    const __hip_bfloat16* __restrict__ A,
    const __hip_bfloat16* __restrict__ Bm,
    const float* __restrict__ b1,
    const float* __restrict__ b2,
    int split,
    float* __restrict__ out1, int N1,
    float* __restrict__ out2, int N2,
    int K) {
    __shared__ alignas(16) __hip_bfloat16 sA[GBM * GBK];
    __shared__ alignas(16) __hip_bfloat16 sB[GBN * GBK];

    const int tid = threadIdx.x;
    const int lane = tid & 63;
    const int wave = tid >> 6;   // 0..3
    const int wy = wave >> 1;    // 0..1
    const int wx = wave & 1;     // 0..1

    const int lrow8 = lane >> 3;                 // 0..7
    const int lchunk = lane & 7;                 // LDS chunk slot (8 elems)
    const int gchunk = lchunk ^ lrow8;           // global chunk fetched into slot

    const int r16 = lane & 15;
    const int qd = lane >> 4;
    const int sw = r16 & 7;  // reader swizzle key

    floatx4 acc[4][4];
#pragma unroll
    for (int i = 0; i < 4; i++)
#pragma unroll
        for (int j = 0; j < 4; j++) acc[i][j] = (floatx4){0.f, 0.f, 0.f, 0.f};

    const size_t arow0 = (size_t)blockIdx.y * GBM;
    const size_t brow0 = (size_t)blockIdx.x * GBN;

    for (int k0 = 0; k0 < K; k0 += GBK) {
        __syncthreads();  // previous ds_reads done before overwrite
#pragma unroll
        for (int half = 0; half < 4; half++) {
            const int rbase = wave * 8 + half * 32;  // wave-uniform
            const __hip_bfloat16* gA =
                A + (arow0 + rbase + lrow8) * K + k0 + gchunk * 8;
            __builtin_amdgcn_global_load_lds(
                (const AS1 unsigned int*)(const void*)gA,
                (AS3 unsigned int*)(void*)(sA + rbase * GBK), 16, 0, 0);
            const __hip_bfloat16* gB =
                Bm + (brow0 + rbase + lrow8) * K + k0 + gchunk * 8;
            __builtin_amdgcn_global_load_lds(
                (const AS1 unsigned int*)(const void*)gB,
                (AS3 unsigned int*)(void*)(sB + rbase * GBK), 16, 0, 0);
        }
        __syncthreads();  // drain staging

#pragma unroll
        for (int kk = 0; kk < 2; kk++) {
            short8 af[4], bf[4];
            const int cs = (qd + 4 * kk);
#pragma unroll
            for (int i = 0; i < 4; i++)
                af[i] = *(const short8*)(sA + (wy * 64 + i * 16 + r16) * GBK +
                                         ((cs ^ sw) * 8));
#pragma unroll
            for (int j = 0; j < 4; j++)
                bf[j] = *(const short8*)(sB + (wx * 64 + j * 16 + r16) * GBK +
                                         ((cs ^ sw) * 8));
#pragma unroll
            for (int i = 0; i < 4; i++)
#pragma unroll
                for (int j = 0; j < 4; j++)
                    acc[i][j] = __builtin_amdgcn_mfma_f32_16x16x32_bf16(
                        af[i], bf[j], acc[i][j], 0, 0, 0);
        }
    }

#pragma unroll
    for (int i = 0; i < 4; i++) {
#pragma unroll
        for (int j = 0; j < 4; j++) {
            const int colb = (int)brow0 + wx * 64 + j * 16 + r16;
            const bool first = colb < split;
            const float bb = first ? b1[colb] : b2[colb - split];
            float* dst = first ? out1 : out2;
            const int nn = first ? N1 : N2;
            const int cc = first ? colb : colb - split;
#pragma unroll
            for (int e = 0; e < 4; e++) {
                const size_t row = arow0 + wy * 64 + i * 16 + qd * 4 + e;
                dst[row * (size_t)nn + cc] = acc[i][j][e] + bb;
            }
        }
    }
}

// ---------------- GEMM 256x256, 8 waves, counted-vmcnt schedule (gemm1) ----
// R5 structure (proven ~90 us / 760 TF). R6's finer 4-phase barrier graft
// REGRESSED (111 us) — R5 schedule kept verbatim.
// R10: XCD-chunked block swizzle. Implicit mapping was XCD = x%8 (x fastest,
// 16y%8==0): B panels XCD-local but ALL 8 XCDs streamed the full 16 MB A.
// Chunked remap gives each XCD 4 contiguous row-tiles -> A panels XCD-local
// (2 MB in 4 MB L2), only B (8 MB) streams from L3. 512 % 8 == 0 -> bijective.
#define TBM 256
#define TBN 256
#define TBK 64

__global__ __launch_bounds__(512) void gemm_bt256(
    const __hip_bfloat16* __restrict__ A,
    const __hip_bfloat16* __restrict__ Bm,
    const float* __restrict__ b1,
    const float* __restrict__ b2,
    int split,
    float* __restrict__ out1, int N1,
    float* __restrict__ out2, int N2,
    int K) {
    __shared__ alignas(16) __hip_bfloat16 sA[2 * TBM * TBK];  // 64 KiB
    __shared__ alignas(16) __hip_bfloat16 sB[2 * TBN * TBK];  // 64 KiB

    const int tid = threadIdx.x;
    const int lane = tid & 63;
    const int wid = tid >> 6;    // 0..7
    const int wrow = wid >> 2;   // 0..1 : M half (128 rows)
    const int wcol = wid & 3;    // 0..3 : N quarter (64 cols)

    const int lrow8 = lane >> 3;
    const int lchunk = lane & 7;
    const int gchunk = lchunk ^ lrow8;  // write-side chunk swizzle

    const int r16 = lane & 15;
    const int qd = lane >> 4;
    const int sw = r16 & 7;  // read-side swizzle key

    // XCD-chunked swizzle (grid is fixed 16 x 32 = 512 blocks for gemm1):
    // lin%8 = XCD; give XCD k the contiguous lin-range [k*64,(k+1)*64) =
    // 4 complete row-tiles (A-locality). bx = swz & 15, by = swz >> 4.
    const int lin = blockIdx.x + (blockIdx.y << 4);
    const int swz = (lin & 7) * 64 + (lin >> 3);
    const int bx = swz & 15;
    const int by = swz >> 4;

    const size_t arow0 = (size_t)by * TBM;
    const size_t brow0 = (size_t)bx * TBN;

    const int nt = K >> 6;  // K-tiles
    const size_t rowskip = (size_t)64 * K;

    const __hip_bfloat16* gA = A + (arow0 + wid * 8 + lrow8) * (size_t)K + gchunk * 8;
    const __hip_bfloat16* gB = Bm + (brow0 + wid * 8 + lrow8) * (size_t)K + gchunk * 8;
    const int ldsAb = wid * 8 * TBK;  // wave-uniform LDS base (elems)

    auto stage = [&](int cc, int ktn) {
#pragma unroll
        for (int rd = 0; rd < 4; ++rd) {
            __builtin_amdgcn_global_load_lds(
                (const AS1 unsigned int*)(const void*)(gA + (size_t)rd * rowskip + ktn * TBK),
                (AS3 unsigned int*)(void*)(sA + cc * (TBM * TBK) + ldsAb + rd * (64 * TBK)),
                16, 0, 0);
            __builtin_amdgcn_global_load_lds(
                (const AS1 unsigned int*)(const void*)(gB + (size_t)rd * rowskip + ktn * TBK),
                (AS3 unsigned int*)(void*)(sB + cc * (TBN * TBK) + ldsAb + rd * (64 * TBK)),
                16, 0, 0);
        }
    };

    floatx4 acc[8][4];
#pragma unroll
    for (int i = 0; i < 8; i++)
#pragma unroll
        for (int j = 0; j < 4; j++) acc[i][j] = (floatx4){0.f, 0.f, 0.f, 0.f};

    const int aofs = (wrow * 128 + r16) * TBK;
    const int bofs = (wcol * 64 + r16) * TBK;
    const int ck0 = ((qd ^ sw) * 8);
    const int ck1 = (((qd + 4) ^ sw) * 8);

    // prologue: stage K-tiles 0 and 1
    stage(0, 0);
    stage(1, 1);
    asm volatile("s_waitcnt vmcnt(8)" ::: "memory");  // K-tile 0 landed
    __builtin_amdgcn_s_barrier();

#pragma unroll 1
    for (int kt = 0; kt < nt; ++kt) {
        const int c = kt & 1;
        const __hip_bfloat16* sAc = sA + c * (TBM * TBK);
        const __hip_bfloat16* sBc = sB + c * (TBN * TBK);

        short8 afr[8][2], bfr[4][2];

        // ---- Phase A: ds_read af rh0 (rf0-3) + bf ch0 (cf0-1); MFMA Q0
#pragma unroll
        for (int f = 0; f < 2; ++f) {
            bfr[f][0] = *(const short8*)(sBc + bofs + f * 1024 + ck0);
            bfr[f][1] = *(const short8*)(sBc + bofs + f * 1024 + ck1);
        }
#pragma unroll
        for (int f = 0; f < 4; ++f) {
            afr[f][0] = *(const short8*)(sAc + aofs + f * 1024 + ck0);
            afr[f][1] = *(const short8*)(sAc + aofs + f * 1024 + ck1);
        }
        __builtin_amdgcn_s_setprio(1);
#pragma unroll
        for (int i = 0; i < 4; ++i)
#pragma unroll
            for (int j = 0; j < 2; ++j)
#pragma unroll
                for (int kk = 0; kk < 2; ++kk)
                    acc[i][j] = __builtin_amdgcn_mfma_f32_16x16x32_bf16(
                        afr[i][kk], bfr[j][kk], acc[i][j], 0, 0, 0);
        __builtin_amdgcn_s_setprio(0);

        // ---- Phase B: ds_read bf ch1 (cf2-3) + af rh1 (rf4-7); MFMA Q1
#pragma unroll
        for (int f = 2; f < 4; ++f) {
            bfr[f][0] = *(const short8*)(sBc + bofs + f * 1024 + ck0);
            bfr[f][1] = *(const short8*)(sBc + bofs + f * 1024 + ck1);
        }
#pragma unroll
        for (int f = 4; f < 8; ++f) {
            afr[f][0] = *(const short8*)(sAc + aofs + f * 1024 + ck0);
            afr[f][1] = *(const short8*)(sAc + aofs + f * 1024 + ck1);
        }
        __builtin_amdgcn_s_setprio(1);
#pragma unroll
        for (int i = 0; i < 4; ++i)
#pragma unroll
            for (int j = 2; j < 4; ++j)
#pragma unroll
            for (int kk = 0; kk < 2; ++kk)
                    acc[i][j] = __builtin_amdgcn_mfma_f32_16x16x32_bf16(
                        afr[i][kk], bfr[j][kk], acc[i][j], 0, 0, 0);
        __builtin_amdgcn_s_setprio(0);

        // ---- boundary 1: all reads of buf[c] complete across the block
        asm volatile("s_waitcnt lgkmcnt(0)" ::: "memory");
        __builtin_amdgcn_sched_barrier(0);
        __builtin_amdgcn_s_barrier();

        // stage kt+2 into buf[c] (now safe to overwrite)
        if (kt + 2 < nt) stage(c, kt + 2);

        // ---- Phase C: pure-register MFMA Q2 (rf4-7 x cf0-1)
        __builtin_amdgcn_s_setprio(1);
#pragma unroll
        for (int i = 4; i < 8; ++i)
#pragma unroll
            for (int j = 0; j < 2; ++j)
#pragma unroll
                for (int kk = 0; kk < 2; ++kk)
                    acc[i][j] = __builtin_amdgcn_mfma_f32_16x16x32_bf16(
                        afr[i][kk], bfr[j][kk], acc[i][j], 0, 0, 0);
        __builtin_amdgcn_s_setprio(0);

        // ---- Phase D: pure-register MFMA Q3 (rf4-7 x cf2-3)
        __builtin_amdgcn_s_setprio(1);
#pragma unroll
        for (int i = 4; i < 8; ++i)
#pragma unroll
            for (int j = 2; j < 4; ++j)
#pragma unroll
                for (int kk = 0; kk < 2; ++kk)
                    acc[i][j] = __builtin_amdgcn_mfma_f32_16x16x32_bf16(
                        afr[i][kk], bfr[j][kk], acc[i][j], 0, 0, 0);
        __builtin_amdgcn_s_setprio(0);

        // ---- boundary 2: kt+1's data landed; kt+2's loads stay in flight
        if (kt + 2 < nt) {
            asm volatile("s_waitcnt vmcnt(8)" ::: "memory");
        } else if (kt + 1 < nt) {
            asm volatile("s_waitcnt vmcnt(0)" ::: "memory");
        }
        if (kt + 1 < nt) __builtin_amdgcn_s_barrier();
    }

    // ---- epilogue (same proven C/D mapping, dual output + bias)
#pragma unroll
    for (int i = 0; i < 8; i++) {
#pragma unroll
        for (int j = 0; j < 4; j++) {
            const int colb = (int)brow0 + wcol * 64 + j * 16 + r16;
            const bool first = colb < split;
            const float bb = first ? b1[colb] : b2[colb - split];
            float* dst = first ? out1 : out2;
            const int nn = first ? N1 : N2;
            const int cc = first ? colb : colb - split;
#pragma unroll
            for (int e = 0; e < 4; e++) {
                const size_t row = arow0 + wrow * 128 + i * 16 + qd * 4 + e;
                dst[row * (size_t)nn + cc] = acc[i][j][e] + bb;
            }
        }
    }
}

// ---------------- attention kernel (8 lanes / position, float8 per lane) ----
// R4: XCD-chunked swizzle (k/v L2 locality). R7: gate fused, bf16 out (proven
// 88 VGPR / 90 us, NATURAL allocation). R2/R9 lesson (final): ANY forced
// occupancy bound on this unrolled body spills catastrophically — plain
// __launch_bounds__(256) only.
// R10: wave-uniform tap skip — when off > nbase+7 the whole wave's 8
// positions are padded (dv == 0 exactly), so the 4 loads + dot + 8 acc-FMAs
// contribute nothing; only the z-term g*|c|*(elu(bias)+1) remains. Branch is
// wave-uniform (no divergence); numerically identical (dv was exactly 0).

static constexpr int OFFS[21] = {1, 2, 3, 4, 6, 8, 12, 16, 24, 32, 48,
                                 64, 96, 128, 192, 256, 384, 512, 768, 1024, 1536};
static constexpr int U1J[21] = {0, 0, 0, 1, 1, 2, 2, 3, 3, 4, 4,
                                5, 5, 6, 6, 7, 7, 8, 8, 9, 9};
static constexpr int U1T[21] = {1, 2, 3, 2, 3, 2, 3, 2, 3, 2, 3,
                                2, 3, 2, 3, 2, 3, 2, 3, 2, 3};
// second user j (tau is always 1); -1 = none
static constexpr int U2J[21] = {-1, 1, -1, 2, -1, 3, -1, 4, -1, 5, -1,
                                6, -1, 7, -1, 8, -1, 9, -1, 10, -1};

static __device__ __forceinline__ float red8(float s) {
    // sum across each 8-lane group; all 8 lanes get the sum.
    int t;
    // quad_perm [1,0,3,2] : lane ^ 1
    t = __builtin_amdgcn_update_dpp(0, __builtin_bit_cast(int, s), 0xB1, 0xF, 0xF, true);
    s += __builtin_bit_cast(float, t);
    // quad_perm [2,3,0,1] : lane ^ 2
    t = __builtin_amdgcn_update_dpp(0, __builtin_bit_cast(int, s), 0x4E, 0xF, 0xF, true);
    s += __builtin_bit_cast(float, t);
    // row_half_mirror : lane i <-> 7-i (within 8-lane half-row)
    t = __builtin_amdgcn_update_dpp(0, __builtin_bit_cast(int, s), 0x141, 0xF, 0xF, true);
    s += __builtin_bit_cast(float, t);
    return s;
}

__global__ __launch_bounds__(256) void attn_kernel(
    const float* __restrict__ qkv,
    const float* __restrict__ scale_gain,       // [11,16]
    const float* __restrict__ W_qscale,         // [11,64]
    const float* __restrict__ identity_bypass,  // [16]
    const float* __restrict__ pos_bias,         // [44,16]
    const float* __restrict__ gate,             // [8192,1024] fp32 (pre-sigmoid)
    __hip_bfloat16* __restrict__ gated) {       // [8192,1024] bf16 out
    const int lane = threadIdx.x & 63;
    const int p = lane >> 3;   // position within wave, 0..7
    const int l = lane & 7;    // d-chunk (8 floats), 0..7

    // XCD-chunked swizzle: hw assigns block i -> XCD i%8; give XCD x the
    // contiguous strip range [x*512, (x+1)*512). 4096 % 8 == 0 -> bijective.
    const int wg = blockIdx.x;
    const int swg = (wg & 7) * 512 + (wg >> 3);

    const int flat = (swg * 4 + (threadIdx.x >> 6)) * 8;  // first n of wave
    const int nbase = flat & (PN - 1);
    const int n = nbase + p;
    const int h = (flat >> 11) & (PH - 1);
    const int b = flat >> 15;

    const size_t base_bn = (size_t)b * PN;
    const int col = h * PHD + l * 8;

    const float* qp = qkv + (base_bn + n) * (3 * PD) + col;
    const float4 qa = *(const float4*)qp;
    const float4 qb = *(const float4*)(qp + 4);
    const float4 k0a = *(const float4*)(qp + PD);
    const float4 k0b = *(const float4*)(qp + PD + 4);
    const float4 v0a = *(const float4*)(qp + 2 * PD);
    const float4 v0b = *(const float4*)(qp + 2 * PD + 4);

    auto dot8 = [](float4 a0, float4 a1, float4 b0, float4 b1) {
        float s = a0.x * b0.x;
        s = fmaf(a0.y, b0.y, s);
        s = fmaf(a0.z, b0.z, s);
        s = fmaf(a0.w, b0.w, s);
        s = fmaf(a1.x, b1.x, s);
        s = fmaf(a1.y, b1.y, s);
        s = fmaf(a1.z, b1.z, s);
        s = fmaf(a1.w, b1.w, s);
        return red8(s);
    };

    const float dot0 = dot8(qa, qb, k0a, k0b);  // k0 regs die here

    // gains = softmax(q @ W_qscale^T + scale_gain[:,h]) over 11 scales
    float g[NSC];
    float mx = -1e30f;
#pragma unroll
    for (int s = 0; s < NSC; s++) {
        const float* wp = W_qscale + s * PHD + l * 8;
        const float4 w0 = *(const float4*)wp;
        const float4 w1 = *(const float4*)(wp + 4);
        g[s] = dot8(qa, qb, w0, w1) + scale_gain[s * PH + h];
        mx = fmaxf(mx, g[s]);
    }
    float ssum = 0.f;
#pragma unroll
    for (int s = 0; s < NSC; s++) {
        g[s] = __expf(g[s] - mx);
        ssum += g[s];
    }
    const float inv = 1.f / ssum;
#pragma unroll
    for (int s = 0; s < NSC; s++) g[s] *= inv;

    const float D4c[4] = {0.4829629131445341f, 0.8365163037378079f,
                          0.2241438680420134f, -0.1294095225512604f};

    float4 o0, o1;
    float z;

    // ---- offset-0 block: 11 tau=0 taps + identity bypass, all scale v0.
    {
        const float bp = log1pf(__expf(identity_bypass[h]));  // softplus
        const float f0 = (dot0 > 0.f ? dot0 : __expf(dot0) - 1.f) + 1.f;
        float wsum = bp * f0;
#pragma unroll
        for (int j = 0; j < NSC; j++) {
            const float xx = dot0 + pos_bias[(j * 4) * PH + h];
            const float feat = (xx > 0.f ? xx : __expf(xx) - 1.f) + 1.f;
            wsum = fmaf(g[j], D4c[0] * feat, wsum);
        }
        z = wsum;
        o0.x = wsum * v0a.x;
        o0.y = wsum * v0a.y;
        o0.z = wsum * v0a.z;
        o0.w = wsum * v0a.w;
        o1.x = wsum * v0b.x;
        o1.y = wsum * v0b.y;
        o1.z = wsum * v0b.z;
        o1.w = wsum * v0b.w;
    }  // v0 regs die here

    // ---- distinct nonzero offsets (each used by 1-2 taps, sharing k/v rows)
#pragma unroll
    for (int t = 0; t < 21; t++) {
        const int off = OFFS[t];
        if (off > nbase + 7) {
            // whole wave padded: dv == 0 exactly -> only z accumulates
            {
                const int j = U1J[t], tau = U1T[t];
                const float xx = pos_bias[(j * 4 + tau) * PH + h];
                const float feat = (xx > 0.f ? xx : __expf(xx) - 1.f) + 1.f;
                z = fmaf(g[j] * fabsf(D4c[tau]), feat, z);
            }
            if (U2J[t] >= 0) {
                const int j = U2J[t];
                const float xx = pos_bias[(j * 4 + 1) * PH + h];
                const float feat = (xx > 0.f ? xx : __expf(xx) - 1.f) + 1.f;
                z = fmaf(g[j] * D4c[1], feat, z);
            }
        } else {
            const bool valid = (n >= off);
            const int idx = valid ? (n - off) : 0;
            const float vm = valid ? 1.f : 0.f;
            const size_t rb = (base_bn + idx) * (3 * PD);
            const float* kp = qkv + rb + PD + col;
            const float* vp = qkv + rb + 2 * PD + col;
            const float4 k4a = *(const float4*)kp;
            const float4 k4b = *(const float4*)(kp + 4);
            const float4 v4a = *(const float4*)vp;
            const float4 v4b = *(const float4*)(vp + 4);
            const float dv = dot8(qa, qb, k4a, k4b) * vm;

            // user 1: (U1J[t], U1T[t])
            float wv, zacc;
            {
                const int j = U1J[t], tau = U1T[t];
                const float xx = dv + pos_bias[(j * 4 + tau) * PH + h];
                const float feat = (xx > 0.f ? xx : __expf(xx) - 1.f) + 1.f;
                const float wp = g[j] * (D4c[tau] * feat);
                zacc = fabsf(wp);  // = g * |coef| * feat  (g,feat >= 0)
                wv = wp;
            }
            // user 2: (U2J[t], tau=1) if present
            if (U2J[t] >= 0) {
                const int j = U2J[t];
                const float xx = dv + pos_bias[(j * 4 + 1) * PH + h];
                const float feat = (xx > 0.f ? xx : __expf(xx) - 1.f) + 1.f;
                const float wp = g[j] * (D4c[1] * feat);
                zacc += wp;  // coef > 0
                wv += wp;
            }
            z += zacc;
            wv *= vm;
            o0.x = fmaf(wv, v4a.x, o0.x);
            o0.y = fmaf(wv, v4a.y, o0.y);
            o0.z = fmaf(wv, v4a.z, o0.z);
            o0.w = fmaf(wv, v4a.w, o0.w);
            o1.x = fmaf(wv, v4b.x, o1.x);
            o1.y = fmaf(wv, v4b.y, o1.y);
            o1.z = fmaf(wv, v4b.z, o1.z);
            o1.w = fmaf(wv, v4b.w, o1.w);
        }
    }

    // ---- tail: normalize, gate (sigmoid), emit bf16
    const float* gp2 = gate + (base_bn + n) * PD + col;
    const float4 ga = *(const float4*)gp2;
    const float4 gb = *(const float4*)(gp2 + 4);
    const float zi = 1.f / (z + 1e-6f);

    short8 r;
    r[0] = (short)bf16bits(o0.x * zi / (1.f + __expf(-ga.x)));
    r[1] = (short)bf16bits(o0.y * zi / (1.f + __expf(-ga.y)));
    r[2] = (short)bf16bits(o0.z * zi / (1.f + __expf(-ga.z)));
    r[3] = (short)bf16bits(o0.w * zi / (1.f + __expf(-ga.w)));
    r[4] = (short)bf16bits(o1.x * zi / (1.f + __expf(-gb.x)));
    r[5] = (short)bf16bits(o1.y * zi / (1.f + __expf(-gb.y)));
    r[6] = (short)bf16bits(o1.z * zi / (1.f + __expf(-gb.z)));
    r[7] = (short)bf16bits(o1.w * zi / (1.f + __expf(-gb.w)));
    *(short8*)(gated + (base_bn + n) * PD + col) = r;
}

// ---------------- launch ----------------
extern "C" void kernel_launch(void* const* d_in, const int* in_sizes, int n_in,
                              void* d_out, int out_size, void* d_ws, size_t ws_size,
                              hipStream_t stream) {
    const float* x = (const float*)d_in[0];
    const float* W_qkv = (const float*)d_in[1];
    const float* b_qkv = (const float*)d_in[2];
    const float* W_out = (const float*)d_in[3];
    const float* b_out = (const float*)d_in[4];
    const float* W_gate = (const float*)d_in[5];
    const float* b_gate = (const float*)d_in[6];
    const float* scale_gain = (const float*)d_in[7];
    const float* W_qscale = (const float*)d_in[8];
    const float* identity_bypass = (const float*)d_in[9];
    const float* pos_bias = (const float*)d_in[10];
    float* out = (float*)d_out;

    const int M = PB * PN;  // 8192
    char* ws = (char*)d_ws;
    size_t off = 0;
    auto alloc = [&](size_t bytes) -> void* {
        void* p = ws + off;
        off += (bytes + 255) & ~(size_t)255;
        return p;
    };
    __hip_bfloat16* x_bf = (__hip_bfloat16*)alloc((size_t)M * PD * 2);
    __hip_bfloat16* wcomb_bf = (__hip_bfloat16*)alloc((size_t)4 * PD * PD * 2);
    __hip_bfloat16* wout_bf = (__hip_bfloat16*)alloc((size_t)PD * PD * 2);
    float* qkv = (float*)alloc((size_t)M * 3 * PD * 4);
    float* gate = (float*)alloc((size_t)M * PD * 4);
    __hip_bfloat16* gated = (__hip_bfloat16*)alloc((size_t)M * PD * 2);

    // merged casts: x -> bf16, weights -> bf16 (one dispatch)
    const int TOT4 = M * PD / 4 + 5 * PD * PD / 4;
    cast_all<<<TOT4 / 256, 256, 0, stream>>>(
        (const float4*)x, (const float4*)W_qkv, (const float4*)W_gate,
        (const float4*)W_out, (ushort4*)x_bf, (ushort4*)wcomb_bf,
        (ushort4*)wout_bf);

    // {qkv, gate} = x @ [W_qkv; W_gate]^T + {b_qkv, b_gate}  (256² pipeline)
    gemm_bt256<<<dim3(4 * PD / TBN, M / TBM), 512, 0, stream>>>(
        x_bf, wcomb_bf, b_qkv, b_gate, 3 * PD, qkv, 3 * PD, gate, PD, PD);

    // attention + gate + bf16 emit -> gated [8192,1024] bf16
    attn_kernel<<<(PB * PH * PN) / 32, 256, 0, stream>>>(
        qkv, scale_gain, W_qscale, identity_bypass, pos_bias, gate, gated);

    // out = gated @ W_out^T + b_out  -> fp32  (N=1024 -> keep 128² for 512 blocks)
    gemm_bt128<<<dim3(PD / GBN, M / GBM), 256, 0, stream>>>(
        gated, wout_bf, b_out, b_out, PD, out, PD, out, PD, PD);
}

// Round 11
// 286.003 us; speedup vs baseline: 1.7382x; 1.0225x over previous
//
#include <hip/hip_runtime.h>
#include <hip/hip_bf16.h>

// Problem constants
#define PB 4
#define PN 2048
#define PD 1024
#define PH 16
#define PHD 64
#define NSC 11

typedef __attribute__((ext_vector_type(8))) short short8;
typedef __attribute__((ext_vector_type(4))) float floatx4;

#define AS1 __attribute__((address_space(1)))
#define AS3 __attribute__((address_space(3)))

static __device__ __forceinline__ unsigned short bf16bits(float f) {
    __hip_bfloat16 h = __float2bfloat16(f);
    return __builtin_bit_cast(unsigned short, h);
}

// ---------------- merged cast kernel (one launch) ----------------
// x (8M floats) -> x_bf ; W_qkv(3M)+W_gate(1M) -> wcomb ; W_out(1M) -> woutb
__global__ void cast_all(const float4* __restrict__ x,
                         const float4* __restrict__ wqkv,
                         const float4* __restrict__ wgate,
                         const float4* __restrict__ wout,
                         ushort4* __restrict__ x_bf,
                         ushort4* __restrict__ wcomb,
                         ushort4* __restrict__ woutb) {
    int i = blockIdx.x * blockDim.x + threadIdx.x;
    const int X4 = PB * PN * PD / 4;
    const int QKV4 = 3 * PD * PD / 4;
    const int G4 = PD * PD / 4;
    float4 v;
    ushort4* dst;
    if (i < X4) {
        v = x[i];
        dst = x_bf + i;
    } else {
        int j = i - X4;
        if (j < QKV4) {
            v = wqkv[j];
            dst = wcomb + j;
        } else if (j < QKV4 + G4) {
            v = wgate[j - QKV4];
            dst = wcomb + j;
        } else {
            v = wout[j - QKV4 - G4];
            dst = woutb + (j - QKV4 - G4);
        }
    }
    ushort4 o;
    o.x = bf16bits(v.x);
    o.y = bf16bits(v.y);
    o.z = bf16bits(v.z);
    o.w = bf16bits(v.w);
    *dst = o;
}

// ---------------- GEMM 256x256, 8 waves, counted-vmcnt schedule (gemm1) ----
// R5 structure (proven). R6's finer 4-phase barrier graft REGRESSED — R5
// schedule kept verbatim. R10: XCD-chunked block swizzle (A panels XCD-local;
// 92 -> 84 us; gain was L2 locality, FETCH unchanged).
#define TBM 256
#define TBN 256
#define TBK 64

__global__ __launch_bounds__(512) void gemm_bt256(
    const __hip_bfloat16* __restrict__ A,
    const __hip_bfloat16* __restrict__ Bm,
    const float* __restrict__ b1,
    const float* __restrict__ b2,
    int split,
    float* __restrict__ out1, int N1,
    float* __restrict__ out2, int N2,
    int K) {
    __shared__ alignas(16) __hip_bfloat16 sA[2 * TBM * TBK];  // 64 KiB
    __shared__ alignas(16) __hip_bfloat16 sB[2 * TBN * TBK];  // 64 KiB

    const int tid = threadIdx.x;
    const int lane = tid & 63;
    const int wid = tid >> 6;    // 0..7
    const int wrow = wid >> 2;   // 0..1 : M half (128 rows)
    const int wcol = wid & 3;    // 0..3 : N quarter (64 cols)

    const int lrow8 = lane >> 3;
    const int lchunk = lane & 7;
    const int gchunk = lchunk ^ lrow8;  // write-side chunk swizzle

    const int r16 = lane & 15;
    const int qd = lane >> 4;
    const int sw = r16 & 7;  // read-side swizzle key

    // XCD-chunked swizzle (grid is fixed 16 x 32 = 512 blocks for gemm1):
    // lin%8 = XCD; give XCD k the contiguous lin-range [k*64,(k+1)*64).
    const int lin = blockIdx.x + (blockIdx.y << 4);
    const int swz = (lin & 7) * 64 + (lin >> 3);
    const int bx = swz & 15;
    const int by = swz >> 4;

    const size_t arow0 = (size_t)by * TBM;
    const size_t brow0 = (size_t)bx * TBN;

    const int nt = K >> 6;  // K-tiles
    const size_t rowskip = (size_t)64 * K;

    const __hip_bfloat16* gA = A + (arow0 + wid * 8 + lrow8) * (size_t)K + gchunk * 8;
    const __hip_bfloat16* gB = Bm + (brow0 + wid * 8 + lrow8) * (size_t)K + gchunk * 8;
    const int ldsAb = wid * 8 * TBK;  // wave-uniform LDS base (elems)

    auto stage = [&](int cc, int ktn) {
#pragma unroll
        for (int rd = 0; rd < 4; ++rd) {
            __builtin_amdgcn_global_load_lds(
                (const AS1 unsigned int*)(const void*)(gA + (size_t)rd * rowskip + ktn * TBK),
                (AS3 unsigned int*)(void*)(sA + cc * (TBM * TBK) + ldsAb + rd * (64 * TBK)),
                16, 0, 0);
            __builtin_amdgcn_global_load_lds(
                (const AS1 unsigned int*)(const void*)(gB + (size_t)rd * rowskip + ktn * TBK),
                (AS3 unsigned int*)(void*)(sB + cc * (TBN * TBK) + ldsAb + rd * (64 * TBK)),
                16, 0, 0);
        }
    };

    floatx4 acc[8][4];
#pragma unroll
    for (int i = 0; i < 8; i++)
#pragma unroll
        for (int j = 0; j < 4; j++) acc[i][j] = (floatx4){0.f, 0.f, 0.f, 0.f};

    const int aofs = (wrow * 128 + r16) * TBK;
    const int bofs = (wcol * 64 + r16) * TBK;
    const int ck0 = ((qd ^ sw) * 8);
    const int ck1 = (((qd + 4) ^ sw) * 8);

    // prologue: stage K-tiles 0 and 1
    stage(0, 0);
    stage(1, 1);
    asm volatile("s_waitcnt vmcnt(8)" ::: "memory");  // K-tile 0 landed
    __builtin_amdgcn_s_barrier();

#pragma unroll 1
    for (int kt = 0; kt < nt; ++kt) {
        const int c = kt & 1;
        const __hip_bfloat16* sAc = sA + c * (TBM * TBK);
        const __hip_bfloat16* sBc = sB + c * (TBN * TBK);

        short8 afr[8][2], bfr[4][2];

        // ---- Phase A: ds_read af rh0 (rf0-3) + bf ch0 (cf0-1); MFMA Q0
#pragma unroll
        for (int f = 0; f < 2; ++f) {
            bfr[f][0] = *(const short8*)(sBc + bofs + f * 1024 + ck0);
            bfr[f][1] = *(const short8*)(sBc + bofs + f * 1024 + ck1);
        }
#pragma unroll
        for (int f = 0; f < 4; ++f) {
            afr[f][0] = *(const short8*)(sAc + aofs + f * 1024 + ck0);
            afr[f][1] = *(const short8*)(sAc + aofs + f * 1024 + ck1);
        }
        __builtin_amdgcn_s_setprio(1);
#pragma unroll
        for (int i = 0; i < 4; ++i)
#pragma unroll
            for (int j = 0; j < 2; ++j)
#pragma unroll
                for (int kk = 0; kk < 2; ++kk)
                    acc[i][j] = __builtin_amdgcn_mfma_f32_16x16x32_bf16(
                        afr[i][kk], bfr[j][kk], acc[i][j], 0, 0, 0);
        __builtin_amdgcn_s_setprio(0);

        // ---- Phase B: ds_read bf ch1 (cf2-3) + af rh1 (rf4-7); MFMA Q1
#pragma unroll
        for (int f = 2; f < 4; ++f) {
            bfr[f][0] = *(const short8*)(sBc + bofs + f * 1024 + ck0);
            bfr[f][1] = *(const short8*)(sBc + bofs + f * 1024 + ck1);
        }
#pragma unroll
        for (int f = 4; f < 8; ++f) {
            afr[f][0] = *(const short8*)(sAc + aofs + f * 1024 + ck0);
            afr[f][1] = *(const short8*)(sAc + aofs + f * 1024 + ck1);
        }
        __builtin_amdgcn_s_setprio(1);
#pragma unroll
        for (int i = 0; i < 4; ++i)
#pragma unroll
            for (int j = 2; j < 4; ++j)
#pragma unroll
            for (int kk = 0; kk < 2; ++kk)
                    acc[i][j] = __builtin_amdgcn_mfma_f32_16x16x32_bf16(
                        afr[i][kk], bfr[j][kk], acc[i][j], 0, 0, 0);
        __builtin_amdgcn_s_setprio(0);

        // ---- boundary 1: all reads of buf[c] complete across the block
        asm volatile("s_waitcnt lgkmcnt(0)" ::: "memory");
        __builtin_amdgcn_sched_barrier(0);
        __builtin_amdgcn_s_barrier();

        // stage kt+2 into buf[c] (now safe to overwrite)
        if (kt + 2 < nt) stage(c, kt + 2);

        // ---- Phase C: pure-register MFMA Q2 (rf4-7 x cf0-1)
        __builtin_amdgcn_s_setprio(1);
#pragma unroll
        for (int i = 4; i < 8; ++i)
#pragma unroll
            for (int j = 0; j < 2; ++j)
#pragma unroll
                for (int kk = 0; kk < 2; ++kk)
                    acc[i][j] = __builtin_amdgcn_mfma_f32_16x16x32_bf16(
                        afr[i][kk], bfr[j][kk], acc[i][j], 0, 0, 0);
        __builtin_amdgcn_s_setprio(0);

        // ---- Phase D: pure-register MFMA Q3 (rf4-7 x cf2-3)
        __builtin_amdgcn_s_setprio(1);
#pragma unroll
        for (int i = 4; i < 8; ++i)
#pragma unroll
            for (int j = 2; j < 4; ++j)
#pragma unroll
                for (int kk = 0; kk < 2; ++kk)
                    acc[i][j] = __builtin_amdgcn_mfma_f32_16x16x32_bf16(
                        afr[i][kk], bfr[j][kk], acc[i][j], 0, 0, 0);
        __builtin_amdgcn_s_setprio(0);

        // ---- boundary 2: kt+1's data landed; kt+2's loads stay in flight
        if (kt + 2 < nt) {
            asm volatile("s_waitcnt vmcnt(8)" ::: "memory");
        } else if (kt + 1 < nt) {
            asm volatile("s_waitcnt vmcnt(0)" ::: "memory");
        }
        if (kt + 1 < nt) __builtin_amdgcn_s_barrier();
    }

    // ---- epilogue (same proven C/D mapping, dual output + bias)
#pragma unroll
    for (int i = 0; i < 8; i++) {
#pragma unroll
        for (int j = 0; j < 4; j++) {
            const int colb = (int)brow0 + wcol * 64 + j * 16 + r16;
            const bool first = colb < split;
            const float bb = first ? b1[colb] : b2[colb - split];
            float* dst = first ? out1 : out2;
            const int nn = first ? N1 : N2;
            const int cc = first ? colb : colb - split;
#pragma unroll
            for (int e = 0; e < 4; e++) {
                const size_t row = arow0 + wrow * 128 + i * 16 + qd * 4 + e;
                dst[row * (size_t)nn + cc] = acc[i][j][e] + bb;
            }
        }
    }
}

// ---------------- GEMM 256x128, 8 waves, counted-vmcnt ring (gemm2) --------
// R11: replaces the single-buffered 2-barrier 128² kernel (640 TF, 2 block
// rounds + vmcnt(0) drain per K-step). Same R5-proven ring: double-buffered
// LDS (96 KiB), distance-2 prefetch, counted vmcnt(6) (6 gloads/stage),
// identical chunk-swizzle / fragment / epilogue mappings. Grid 8 x 32 = 256
// blocks = exactly 1/CU, single round, no tail. Wave tile 128x32 (acc[8][2]).
#define UBM 256
#define UBN 128
#define UBK 64

__global__ __launch_bounds__(512) void gemm_bt256x128(
    const __hip_bfloat16* __restrict__ A,
    const __hip_bfloat16* __restrict__ Bm,
    const float* __restrict__ bias,
    float* __restrict__ out, int N1, int K) {
    __shared__ alignas(16) __hip_bfloat16 sA[2 * UBM * UBK];  // 64 KiB
    __shared__ alignas(16) __hip_bfloat16 sB[2 * UBN * UBK];  // 32 KiB

    const int tid = threadIdx.x;
    const int lane = tid & 63;
    const int wid = tid >> 6;    // 0..7
    const int wrow = wid >> 2;   // 0..1 : M half (128 rows)
    const int wcol = wid & 3;    // 0..3 : N quarter (32 cols)

    const int lrow8 = lane >> 3;
    const int gchunk = (lane & 7) ^ lrow8;  // write-side chunk swizzle

    const int r16 = lane & 15;
    const int qd = lane >> 4;
    const int sw = r16 & 7;  // read-side swizzle key

    // grid 8 x 32 = 256 blocks; XCD-chunked swizzle (256 % 8 == 0, bijective)
    const int lin = blockIdx.x + (blockIdx.y << 3);
    const int swz = (lin & 7) * 32 + (lin >> 3);
    const int bx = swz & 7;
    const int by = swz >> 3;

    const size_t arow0 = (size_t)by * UBM;
    const size_t brow0 = (size_t)bx * UBN;

    const int nt = K >> 6;
    const size_t rowskip = (size_t)64 * K;

    const __hip_bfloat16* gA = A + (arow0 + wid * 8 + lrow8) * (size_t)K + gchunk * 8;
    const __hip_bfloat16* gB = Bm + (brow0 + wid * 8 + lrow8) * (size_t)K + gchunk * 8;
    const int ldsAb = wid * 8 * UBK;  // wave-uniform LDS base (elems)

    // 4 A-rounds (256 rows) + 2 B-rounds (128 rows) = 6 gloads per stage
    auto stage = [&](int cc, int ktn) {
#pragma unroll
        for (int rd = 0; rd < 4; ++rd)
            __builtin_amdgcn_global_load_lds(
                (const AS1 unsigned int*)(const void*)(gA + (size_t)rd * rowskip + ktn * UBK),
                (AS3 unsigned int*)(void*)(sA + cc * (UBM * UBK) + ldsAb + rd * (64 * UBK)),
                16, 0, 0);
#pragma unroll
        for (int rd = 0; rd < 2; ++rd)
            __builtin_amdgcn_global_load_lds(
                (const AS1 unsigned int*)(const void*)(gB + (size_t)rd * rowskip + ktn * UBK),
                (AS3 unsigned int*)(void*)(sB + cc * (UBN * UBK) + ldsAb + rd * (64 * UBK)),
                16, 0, 0);
    };

    floatx4 acc[8][2];
#pragma unroll
    for (int i = 0; i < 8; i++)
#pragma unroll
        for (int j = 0; j < 2; j++) acc[i][j] = (floatx4){0.f, 0.f, 0.f, 0.f};

    const int aofs = (wrow * 128 + r16) * UBK;
    const int bofs = (wcol * 32 + r16) * UBK;
    const int ck0 = ((qd ^ sw) * 8);
    const int ck1 = (((qd + 4) ^ sw) * 8);

    // prologue: stage K-tiles 0 and 1 (12 loads); wait tile 0 (<=6 left)
    stage(0, 0);
    stage(1, 1);
    asm volatile("s_waitcnt vmcnt(6)" ::: "memory");
    __builtin_amdgcn_s_barrier();

#pragma unroll 1
    for (int kt = 0; kt < nt; ++kt) {
        const int c = kt & 1;
        const __hip_bfloat16* sAc = sA + c * (UBM * UBK);
        const __hip_bfloat16* sBc = sB + c * (UBN * UBK);

        short8 afr[8][2], bfr[2][2];

        // ---- Phase A: ds_read bfr (4) + afr[0..3] (8); MFMA i0-1
#pragma unroll
        for (int f = 0; f < 2; ++f) {
            bfr[f][0] = *(const short8*)(sBc + bofs + f * 1024 + ck0);
            bfr[f][1] = *(const short8*)(sBc + bofs + f * 1024 + ck1);
        }
#pragma unroll
        for (int f = 0; f < 4; ++f) {
            afr[f][0] = *(const short8*)(sAc + aofs + f * 1024 + ck0);
            afr[f][1] = *(const short8*)(sAc + aofs + f * 1024 + ck1);
        }
        __builtin_amdgcn_s_setprio(1);
#pragma unroll
        for (int i = 0; i < 2; ++i)
#pragma unroll
            for (int j = 0; j < 2; ++j)
#pragma unroll
                for (int kk = 0; kk < 2; ++kk)
                    acc[i][j] = __builtin_amdgcn_mfma_f32_16x16x32_bf16(
                        afr[i][kk], bfr[j][kk], acc[i][j], 0, 0, 0);
        __builtin_amdgcn_s_setprio(0);

        // ---- Phase B: ds_read afr[4..7] (8); MFMA i2-3
#pragma unroll
        for (int f = 4; f < 8; ++f) {
            afr[f][0] = *(const short8*)(sAc + aofs + f * 1024 + ck0);
            afr[f][1] = *(const short8*)(sAc + aofs + f * 1024 + ck1);
        }
        __builtin_amdgcn_s_setprio(1);
#pragma unroll
        for (int i = 2; i < 4; ++i)
#pragma unroll
            for (int j = 0; j < 2; ++j)
#pragma unroll
                for (int kk = 0; kk < 2; ++kk)
                    acc[i][j] = __builtin_amdgcn_mfma_f32_16x16x32_bf16(
                        afr[i][kk], bfr[j][kk], acc[i][j], 0, 0, 0);
        __builtin_amdgcn_s_setprio(0);

        // ---- boundary 1: all reads of buf[c] complete across the block
        asm volatile("s_waitcnt lgkmcnt(0)" ::: "memory");
        __builtin_amdgcn_sched_barrier(0);
        __builtin_amdgcn_s_barrier();

        // stage kt+2 into buf[c] (now safe to overwrite)
        if (kt + 2 < nt) stage(c, kt + 2);

        // ---- Phase C: pure-register MFMA i4-5
        __builtin_amdgcn_s_setprio(1);
#pragma unroll
        for (int i = 4; i < 6; ++i)
#pragma unroll
            for (int j = 0; j < 2; ++j)
#pragma unroll
                for (int kk = 0; kk < 2; ++kk)
                    acc[i][j] = __builtin_amdgcn_mfma_f32_16x16x32_bf16(
                        afr[i][kk], bfr[j][kk], acc[i][j], 0, 0, 0);
        __builtin_amdgcn_s_setprio(0);

        // ---- Phase D: pure-register MFMA i6-7
        __builtin_amdgcn_s_setprio(1);
#pragma unroll
        for (int i = 6; i < 8; ++i)
#pragma unroll
            for (int j = 0; j < 2; ++j)
#pragma unroll
                for (int kk = 0; kk < 2; ++kk)
                    acc[i][j] = __builtin_amdgcn_mfma_f32_16x16x32_bf16(
                        afr[i][kk], bfr[j][kk], acc[i][j], 0, 0, 0);
        __builtin_amdgcn_s_setprio(0);

        // ---- boundary 2: kt+1's 6 loads landed; kt+2's 6 stay in flight
        if (kt + 2 < nt) {
            asm volatile("s_waitcnt vmcnt(6)" ::: "memory");
        } else if (kt + 1 < nt) {
            asm volatile("s_waitcnt vmcnt(0)" ::: "memory");
        }
        if (kt + 1 < nt) __builtin_amdgcn_s_barrier();
    }

    // ---- epilogue (proven C/D mapping, single output + bias)
#pragma unroll
    for (int i = 0; i < 8; i++) {
#pragma unroll
        for (int j = 0; j < 2; j++) {
            const int colb = (int)brow0 + wcol * 32 + j * 16 + r16;
            const float bb = bias[colb];
#pragma unroll
            for (int e = 0; e < 4; e++) {
                const size_t row = arow0 + wrow * 128 + i * 16 + qd * 4 + e;
                out[row * (size_t)N1 + colb] = acc[i][j][e] + bb;
            }
        }
    }
}

// ---------------- attention kernel (8 lanes / position, float8 per lane) ----
// R4: XCD-chunked swizzle (k/v L2 locality). R7: gate fused, bf16 out (proven
// 88 VGPR, NATURAL allocation). R2/R9 lesson (final): ANY forced occupancy
// bound on this unrolled body spills catastrophically — plain
// __launch_bounds__(256) only. R10: wave-uniform tap skip (dv==0 exactly for
// fully-padded waves; z-only path). Proven ~82 us; frozen.

static constexpr int OFFS[21] = {1, 2, 3, 4, 6, 8, 12, 16, 24, 32, 48,
                                 64, 96, 128, 192, 256, 384, 512, 768, 1024, 1536};
static constexpr int U1J[21] = {0, 0, 0, 1, 1, 2, 2, 3, 3, 4, 4,
                                5, 5, 6, 6, 7, 7, 8, 8, 9, 9};
static constexpr int U1T[21] = {1, 2, 3, 2, 3, 2, 3, 2, 3, 2, 3,
                                2, 3, 2, 3, 2, 3, 2, 3, 2, 3};
// second user j (tau is always 1); -1 = none
static constexpr int U2J[21] = {-1, 1, -1, 2, -1, 3, -1, 4, -1, 5, -1,
                                6, -1, 7, -1, 8, -1, 9, -1, 10, -1};

static __device__ __forceinline__ float red8(float s) {
    // sum across each 8-lane group; all 8 lanes get the sum.
    int t;
    // quad_perm [1,0,3,2] : lane ^ 1
    t = __builtin_amdgcn_update_dpp(0, __builtin_bit_cast(int, s), 0xB1, 0xF, 0xF, true);
    s += __builtin_bit_cast(float, t);
    // quad_perm [2,3,0,1] : lane ^ 2
    t = __builtin_amdgcn_update_dpp(0, __builtin_bit_cast(int, s), 0x4E, 0xF, 0xF, true);
    s += __builtin_bit_cast(float, t);
    // row_half_mirror : lane i <-> 7-i (within 8-lane half-row)
    t = __builtin_amdgcn_update_dpp(0, __builtin_bit_cast(int, s), 0x141, 0xF, 0xF, true);
    s += __builtin_bit_cast(float, t);
    return s;
}

__global__ __launch_bounds__(256) void attn_kernel(
    const float* __restrict__ qkv,
    const float* __restrict__ scale_gain,       // [11,16]
    const float* __restrict__ W_qscale,         // [11,64]
    const float* __restrict__ identity_bypass,  // [16]
    const float* __restrict__ pos_bias,         // [44,16]
    const float* __restrict__ gate,             // [8192,1024] fp32 (pre-sigmoid)
    __hip_bfloat16* __restrict__ gated) {       // [8192,1024] bf16 out
    const int lane = threadIdx.x & 63;
    const int p = lane >> 3;   // position within wave, 0..7
    const int l = lane & 7;    // d-chunk (8 floats), 0..7

    // XCD-chunked swizzle: hw assigns block i -> XCD i%8; give XCD x the
    // contiguous strip range [x*512, (x+1)*512). 4096 % 8 == 0 -> bijective.
    const int wg = blockIdx.x;
    const int swg = (wg & 7) * 512 + (wg >> 3);

    const int flat = (swg * 4 + (threadIdx.x >> 6)) * 8;  // first n of wave
    const int nbase = flat & (PN - 1);
    const int n = nbase + p;
    const int h = (flat >> 11) & (PH - 1);
    const int b = flat >> 15;

    const size_t base_bn = (size_t)b * PN;
    const int col = h * PHD + l * 8;

    const float* qp = qkv + (base_bn + n) * (3 * PD) + col;
    const float4 qa = *(const float4*)qp;
    const float4 qb = *(const float4*)(qp + 4);
    const float4 k0a = *(const float4*)(qp + PD);
    const float4 k0b = *(const float4*)(qp + PD + 4);
    const float4 v0a = *(const float4*)(qp + 2 * PD);
    const float4 v0b = *(const float4*)(qp + 2 * PD + 4);

    auto dot8 = [](float4 a0, float4 a1, float4 b0, float4 b1) {
        float s = a0.x * b0.x;
        s = fmaf(a0.y, b0.y, s);
        s = fmaf(a0.z, b0.z, s);
        s = fmaf(a0.w, b0.w, s);
        s = fmaf(a1.x, b1.x, s);
        s = fmaf(a1.y, b1.y, s);
        s = fmaf(a1.z, b1.z, s);
        s = fmaf(a1.w, b1.w, s);
        return red8(s);
    };

    const float dot0 = dot8(qa, qb, k0a, k0b);  // k0 regs die here

    // gains = softmax(q @ W_qscale^T + scale_gain[:,h]) over 11 scales
    float g[NSC];
    float mx = -1e30f;
#pragma unroll
    for (int s = 0; s < NSC; s++) {
        const float* wp = W_qscale + s * PHD + l * 8;
        const float4 w0 = *(const float4*)wp;
        const float4 w1 = *(const float4*)(wp + 4);
        g[s] = dot8(qa, qb, w0, w1) + scale_gain[s * PH + h];
        mx = fmaxf(mx, g[s]);
    }
    float ssum = 0.f;
#pragma unroll
    for (int s = 0; s < NSC; s++) {
        g[s] = __expf(g[s] - mx);
        ssum += g[s];
    }
    const float inv = 1.f / ssum;
#pragma unroll
    for (int s = 0; s < NSC; s++) g[s] *= inv;

    const float D4c[4] = {0.4829629131445341f, 0.8365163037378079f,
                          0.2241438680420134f, -0.1294095225512604f};

    float4 o0, o1;
    float z;

    // ---- offset-0 block: 11 tau=0 taps + identity bypass, all scale v0.
    {
        const float bp = log1pf(__expf(identity_bypass[h]));  // softplus
        const float f0 = (dot0 > 0.f ? dot0 : __expf(dot0) - 1.f) + 1.f;
        float wsum = bp * f0;
#pragma unroll
        for (int j = 0; j < NSC; j++) {
            const float xx = dot0 + pos_bias[(j * 4) * PH + h];
            const float feat = (xx > 0.f ? xx : __expf(xx) - 1.f) + 1.f;
            wsum = fmaf(g[j], D4c[0] * feat, wsum);
        }
        z = wsum;
        o0.x = wsum * v0a.x;
        o0.y = wsum * v0a.y;
        o0.z = wsum * v0a.z;
        o0.w = wsum * v0a.w;
        o1.x = wsum * v0b.x;
        o1.y = wsum * v0b.y;
        o1.z = wsum * v0b.z;
        o1.w = wsum * v0b.w;
    }  // v0 regs die here

    // ---- distinct nonzero offsets (each used by 1-2 taps, sharing k/v rows)
#pragma unroll
    for (int t = 0; t < 21; t++) {
        const int off = OFFS[t];
        if (off > nbase + 7) {
            // whole wave padded: dv == 0 exactly -> only z accumulates
            {
                const int j = U1J[t], tau = U1T[t];
                const float xx = pos_bias[(j * 4 + tau) * PH + h];
                const float feat = (xx > 0.f ? xx : __expf(xx) - 1.f) + 1.f;
                z = fmaf(g[j] * fabsf(D4c[tau]), feat, z);
            }
            if (U2J[t] >= 0) {
                const int j = U2J[t];
                const float xx = pos_bias[(j * 4 + 1) * PH + h];
                const float feat = (xx > 0.f ? xx : __expf(xx) - 1.f) + 1.f;
                z = fmaf(g[j] * D4c[1], feat, z);
            }
        } else {
            const bool valid = (n >= off);
            const int idx = valid ? (n - off) : 0;
            const float vm = valid ? 1.f : 0.f;
            const size_t rb = (base_bn + idx) * (3 * PD);
            const float* kp = qkv + rb + PD + col;
            const float* vp = qkv + rb + 2 * PD + col;
            const float4 k4a = *(const float4*)kp;
            const float4 k4b = *(const float4*)(kp + 4);
            const float4 v4a = *(const float4*)vp;
            const float4 v4b = *(const float4*)(vp + 4);
            const float dv = dot8(qa, qb, k4a, k4b) * vm;

            // user 1: (U1J[t], U1T[t])
            float wv, zacc;
            {
                const int j = U1J[t], tau = U1T[t];
                const float xx = dv + pos_bias[(j * 4 + tau) * PH + h];
                const float feat = (xx > 0.f ? xx : __expf(xx) - 1.f) + 1.f;
                const float wp = g[j] * (D4c[tau] * feat);
                zacc = fabsf(wp);  // = g * |coef| * feat  (g,feat >= 0)
                wv = wp;
            }
            // user 2: (U2J[t], tau=1) if present
            if (U2J[t] >= 0) {
                const int j = U2J[t];
                const float xx = dv + pos_bias[(j * 4 + 1) * PH + h];
                const float feat = (xx > 0.f ? xx : __expf(xx) - 1.f) + 1.f;
                const float wp = g[j] * (D4c[1] * feat);
                zacc += wp;  // coef > 0
                wv += wp;
            }
            z += zacc;
            wv *= vm;
            o0.x = fmaf(wv, v4a.x, o0.x);
            o0.y = fmaf(wv, v4a.y, o0.y);
            o0.z = fmaf(wv, v4a.z, o0.z);
            o0.w = fmaf(wv, v4a.w, o0.w);
            o1.x = fmaf(wv, v4b.x, o1.x);
            o1.y = fmaf(wv, v4b.y, o1.y);
            o1.z = fmaf(wv, v4b.z, o1.z);
            o1.w = fmaf(wv, v4b.w, o1.w);
        }
    }

    // ---- tail: normalize, gate (sigmoid), emit bf16
    const float* gp2 = gate + (base_bn + n) * PD + col;
    const float4 ga = *(const float4*)gp2;
    const float4 gb = *(const float4*)(gp2 + 4);
    const float zi = 1.f / (z + 1e-6f);

    short8 r;
    r[0] = (short)bf16bits(o0.x * zi / (1.f + __expf(-ga.x)));
    r[1] = (short)bf16bits(o0.y * zi / (1.f + __expf(-ga.y)));
    r[2] = (short)bf16bits(o0.z * zi / (1.f + __expf(-ga.z)));
    r[3] = (short)bf16bits(o0.w * zi / (1.f + __expf(-ga.w)));
    r[4] = (short)bf16bits(o1.x * zi / (1.f + __expf(-gb.x)));
    r[5] = (short)bf16bits(o1.y * zi / (1.f + __expf(-gb.y)));
    r[6] = (short)bf16bits(o1.z * zi / (1.f + __expf(-gb.z)));
    r[7] = (short)bf16bits(o1.w * zi / (1.f + __expf(-gb.w)));
    *(short8*)(gated + (base_bn + n) * PD + col) = r;
}

// ---------------- launch ----------------
extern "C" void kernel_launch(void* const* d_in, const int* in_sizes, int n_in,
                              void* d_out, int out_size, void* d_ws, size_t ws_size,
                              hipStream_t stream) {
    const float* x = (const float*)d_in[0];
    const float* W_qkv = (const float*)d_in[1];
    const float* b_qkv = (const float*)d_in[2];
    const float* W_out = (const float*)d_in[3];
    const float* b_out = (const float*)d_in[4];
    const float* W_gate = (const float*)d_in[5];
    const float* b_gate = (const float*)d_in[6];
    const float* scale_gain = (const float*)d_in[7];
    const float* W_qscale = (const float*)d_in[8];
    const float* identity_bypass = (const float*)d_in[9];
    const float* pos_bias = (const float*)d_in[10];
    float* out = (float*)d_out;

    const int M = PB * PN;  // 8192
    char* ws = (char*)d_ws;
    size_t off = 0;
    auto alloc = [&](size_t bytes) -> void* {
        void* p = ws + off;
        off += (bytes + 255) & ~(size_t)255;
        return p;
    };
    __hip_bfloat16* x_bf = (__hip_bfloat16*)alloc((size_t)M * PD * 2);
    __hip_bfloat16* wcomb_bf = (__hip_bfloat16*)alloc((size_t)4 * PD * PD * 2);
    __hip_bfloat16* wout_bf = (__hip_bfloat16*)alloc((size_t)PD * PD * 2);
    float* qkv = (float*)alloc((size_t)M * 3 * PD * 4);
    float* gate = (float*)alloc((size_t)M * PD * 4);
    __hip_bfloat16* gated = (__hip_bfloat16*)alloc((size_t)M * PD * 2);

    // merged casts: x -> bf16, weights -> bf16 (one dispatch)
    const int TOT4 = M * PD / 4 + 5 * PD * PD / 4;
    cast_all<<<TOT4 / 256, 256, 0, stream>>>(
        (const float4*)x, (const float4*)W_qkv, (const float4*)W_gate,
        (const float4*)W_out, (ushort4*)x_bf, (ushort4*)wcomb_bf,
        (ushort4*)wout_bf);

    // {qkv, gate} = x @ [W_qkv; W_gate]^T + {b_qkv, b_gate}  (256² pipeline)
    gemm_bt256<<<dim3(4 * PD / TBN, M / TBM), 512, 0, stream>>>(
        x_bf, wcomb_bf, b_qkv, b_gate, 3 * PD, qkv, 3 * PD, gate, PD, PD);

    // attention + gate + bf16 emit -> gated [8192,1024] bf16
    attn_kernel<<<(PB * PH * PN) / 32, 256, 0, stream>>>(
        qkv, scale_gain, W_qscale, identity_bypass, pos_bias, gate, gated);

    // out = gated @ W_out^T + b_out  (256x128 ring, 256 blocks = 1/CU, 1 round)
    gemm_bt256x128<<<dim3(PD / UBN, M / UBM), 512, 0, stream>>>(
        gated, wout_bf, b_out, out, PD, PD);
}

// Round 12
// 277.253 us; speedup vs baseline: 1.7931x; 1.0316x over previous
//
#include <hip/hip_runtime.h>
#include <hip/hip_bf16.h>

// Problem constants
#define PB 4
#define PN 2048
#define PD 1024
#define PH 16
#define PHD 64
#define NSC 11

typedef __attribute__((ext_vector_type(8))) short short8;
typedef __attribute__((ext_vector_type(4))) float floatx4;

#define AS1 __attribute__((address_space(1)))
#define AS3 __attribute__((address_space(3)))

static __device__ __forceinline__ unsigned short bf16bits(float f) {
    __hip_bfloat16 h = __float2bfloat16(f);
    return __builtin_bit_cast(unsigned short, h);
}

// ---------------- merged cast kernel (one launch) ----------------
// x (8M floats) -> x_bf ; W_qkv(3M)+W_gate(1M) -> wcomb ; W_out(1M) -> woutb
__global__ void cast_all(const float4* __restrict__ x,
                         const float4* __restrict__ wqkv,
                         const float4* __restrict__ wgate,
                         const float4* __restrict__ wout,
                         ushort4* __restrict__ x_bf,
                         ushort4* __restrict__ wcomb,
                         ushort4* __restrict__ woutb) {
    int i = blockIdx.x * blockDim.x + threadIdx.x;
    const int X4 = PB * PN * PD / 4;
    const int QKV4 = 3 * PD * PD / 4;
    const int G4 = PD * PD / 4;
    float4 v;
    ushort4* dst;
    if (i < X4) {
        v = x[i];
        dst = x_bf + i;
    } else {
        int j = i - X4;
        if (j < QKV4) {
            v = wqkv[j];
            dst = wcomb + j;
        } else if (j < QKV4 + G4) {
            v = wgate[j - QKV4];
            dst = wcomb + j;
        } else {
            v = wout[j - QKV4 - G4];
            dst = woutb + (j - QKV4 - G4);
        }
    }
    ushort4 o;
    o.x = bf16bits(v.x);
    o.y = bf16bits(v.y);
    o.z = bf16bits(v.z);
    o.w = bf16bits(v.w);
    *dst = o;
}

// ---------------- GEMM 256x256, 8 waves, counted-vmcnt schedule (gemm1) ----
// R5 structure (proven). R6's finer 4-phase barrier graft REGRESSED — R5
// schedule kept verbatim. R10: XCD-chunked block swizzle (A panels XCD-local;
// 92 -> 84 us; gain was L2 locality, FETCH unchanged). FROZEN.
#define TBM 256
#define TBN 256
#define TBK 64

__global__ __launch_bounds__(512) void gemm_bt256(
    const __hip_bfloat16* __restrict__ A,
    const __hip_bfloat16* __restrict__ Bm,
    const float* __restrict__ b1,
    const float* __restrict__ b2,
    int split,
    float* __restrict__ out1, int N1,
    float* __restrict__ out2, int N2,
    int K) {
    __shared__ alignas(16) __hip_bfloat16 sA[2 * TBM * TBK];  // 64 KiB
    __shared__ alignas(16) __hip_bfloat16 sB[2 * TBN * TBK];  // 64 KiB

    const int tid = threadIdx.x;
    const int lane = tid & 63;
    const int wid = tid >> 6;    // 0..7
    const int wrow = wid >> 2;   // 0..1 : M half (128 rows)
    const int wcol = wid & 3;    // 0..3 : N quarter (64 cols)

    const int lrow8 = lane >> 3;
    const int lchunk = lane & 7;
    const int gchunk = lchunk ^ lrow8;  // write-side chunk swizzle

    const int r16 = lane & 15;
    const int qd = lane >> 4;
    const int sw = r16 & 7;  // read-side swizzle key

    // XCD-chunked swizzle (grid is fixed 16 x 32 = 512 blocks for gemm1):
    // lin%8 = XCD; give XCD k the contiguous lin-range [k*64,(k+1)*64).
    const int lin = blockIdx.x + (blockIdx.y << 4);
    const int swz = (lin & 7) * 64 + (lin >> 3);
    const int bx = swz & 15;
    const int by = swz >> 4;

    const size_t arow0 = (size_t)by * TBM;
    const size_t brow0 = (size_t)bx * TBN;

    const int nt = K >> 6;  // K-tiles
    const size_t rowskip = (size_t)64 * K;

    const __hip_bfloat16* gA = A + (arow0 + wid * 8 + lrow8) * (size_t)K + gchunk * 8;
    const __hip_bfloat16* gB = Bm + (brow0 + wid * 8 + lrow8) * (size_t)K + gchunk * 8;
    const int ldsAb = wid * 8 * TBK;  // wave-uniform LDS base (elems)

    auto stage = [&](int cc, int ktn) {
#pragma unroll
        for (int rd = 0; rd < 4; ++rd) {
            __builtin_amdgcn_global_load_lds(
                (const AS1 unsigned int*)(const void*)(gA + (size_t)rd * rowskip + ktn * TBK),
                (AS3 unsigned int*)(void*)(sA + cc * (TBM * TBK) + ldsAb + rd * (64 * TBK)),
                16, 0, 0);
            __builtin_amdgcn_global_load_lds(
                (const AS1 unsigned int*)(const void*)(gB + (size_t)rd * rowskip + ktn * TBK),
                (AS3 unsigned int*)(void*)(sB + cc * (TBN * TBK) + ldsAb + rd * (64 * TBK)),
                16, 0, 0);
        }
    };

    floatx4 acc[8][4];
#pragma unroll
    for (int i = 0; i < 8; i++)
#pragma unroll
        for (int j = 0; j < 4; j++) acc[i][j] = (floatx4){0.f, 0.f, 0.f, 0.f};

    const int aofs = (wrow * 128 + r16) * TBK;
    const int bofs = (wcol * 64 + r16) * TBK;
    const int ck0 = ((qd ^ sw) * 8);
    const int ck1 = (((qd + 4) ^ sw) * 8);

    // prologue: stage K-tiles 0 and 1
    stage(0, 0);
    stage(1, 1);
    asm volatile("s_waitcnt vmcnt(8)" ::: "memory");  // K-tile 0 landed
    __builtin_amdgcn_s_barrier();

#pragma unroll 1
    for (int kt = 0; kt < nt; ++kt) {
        const int c = kt & 1;
        const __hip_bfloat16* sAc = sA + c * (TBM * TBK);
        const __hip_bfloat16* sBc = sB + c * (TBN * TBK);

        short8 afr[8][2], bfr[4][2];

        // ---- Phase A: ds_read af rh0 (rf0-3) + bf ch0 (cf0-1); MFMA Q0
#pragma unroll
        for (int f = 0; f < 2; ++f) {
            bfr[f][0] = *(const short8*)(sBc + bofs + f * 1024 + ck0);
            bfr[f][1] = *(const short8*)(sBc + bofs + f * 1024 + ck1);
        }
#pragma unroll
        for (int f = 0; f < 4; ++f) {
            afr[f][0] = *(const short8*)(sAc + aofs + f * 1024 + ck0);
            afr[f][1] = *(const short8*)(sAc + aofs + f * 1024 + ck1);
        }
        __builtin_amdgcn_s_setprio(1);
#pragma unroll
        for (int i = 0; i < 4; ++i)
#pragma unroll
            for (int j = 0; j < 2; ++j)
#pragma unroll
                for (int kk = 0; kk < 2; ++kk)
                    acc[i][j] = __builtin_amdgcn_mfma_f32_16x16x32_bf16(
                        afr[i][kk], bfr[j][kk], acc[i][j], 0, 0, 0);
        __builtin_amdgcn_s_setprio(0);

        // ---- Phase B: ds_read bf ch1 (cf2-3) + af rh1 (rf4-7); MFMA Q1
#pragma unroll
        for (int f = 2; f < 4; ++f) {
            bfr[f][0] = *(const short8*)(sBc + bofs + f * 1024 + ck0);
            bfr[f][1] = *(const short8*)(sBc + bofs + f * 1024 + ck1);
        }
#pragma unroll
        for (int f = 4; f < 8; ++f) {
            afr[f][0] = *(const short8*)(sAc + aofs + f * 1024 + ck0);
            afr[f][1] = *(const short8*)(sAc + aofs + f * 1024 + ck1);
        }
        __builtin_amdgcn_s_setprio(1);
#pragma unroll
        for (int i = 0; i < 4; ++i)
#pragma unroll
            for (int j = 2; j < 4; ++j)
#pragma unroll
            for (int kk = 0; kk < 2; ++kk)
                    acc[i][j] = __builtin_amdgcn_mfma_f32_16x16x32_bf16(
                        afr[i][kk], bfr[j][kk], acc[i][j], 0, 0, 0);
        __builtin_amdgcn_s_setprio(0);

        // ---- boundary 1: all reads of buf[c] complete across the block
        asm volatile("s_waitcnt lgkmcnt(0)" ::: "memory");
        __builtin_amdgcn_sched_barrier(0);
        __builtin_amdgcn_s_barrier();

        // stage kt+2 into buf[c] (now safe to overwrite)
        if (kt + 2 < nt) stage(c, kt + 2);

        // ---- Phase C: pure-register MFMA Q2 (rf4-7 x cf0-1)
        __builtin_amdgcn_s_setprio(1);
#pragma unroll
        for (int i = 4; i < 8; ++i)
#pragma unroll
            for (int j = 0; j < 2; ++j)
#pragma unroll
                for (int kk = 0; kk < 2; ++kk)
                    acc[i][j] = __builtin_amdgcn_mfma_f32_16x16x32_bf16(
                        afr[i][kk], bfr[j][kk], acc[i][j], 0, 0, 0);
        __builtin_amdgcn_s_setprio(0);

        // ---- Phase D: pure-register MFMA Q3 (rf4-7 x cf2-3)
        __builtin_amdgcn_s_setprio(1);
#pragma unroll
        for (int i = 4; i < 8; ++i)
#pragma unroll
            for (int j = 2; j < 4; ++j)
#pragma unroll
                for (int kk = 0; kk < 2; ++kk)
                    acc[i][j] = __builtin_amdgcn_mfma_f32_16x16x32_bf16(
                        afr[i][kk], bfr[j][kk], acc[i][j], 0, 0, 0);
        __builtin_amdgcn_s_setprio(0);

        // ---- boundary 2: kt+1's data landed; kt+2's loads stay in flight
        if (kt + 2 < nt) {
            asm volatile("s_waitcnt vmcnt(8)" ::: "memory");
        } else if (kt + 1 < nt) {
            asm volatile("s_waitcnt vmcnt(0)" ::: "memory");
        }
        if (kt + 1 < nt) __builtin_amdgcn_s_barrier();
    }

    // ---- epilogue (same proven C/D mapping, dual output + bias)
#pragma unroll
    for (int i = 0; i < 8; i++) {
#pragma unroll
        for (int j = 0; j < 4; j++) {
            const int colb = (int)brow0 + wcol * 64 + j * 16 + r16;
            const bool first = colb < split;
            const float bb = first ? b1[colb] : b2[colb - split];
            float* dst = first ? out1 : out2;
            const int nn = first ? N1 : N2;
            const int cc = first ? colb : colb - split;
#pragma unroll
            for (int e = 0; e < 4; e++) {
                const size_t row = arow0 + wrow * 128 + i * 16 + qd * 4 + e;
                dst[row * (size_t)nn + cc] = acc[i][j][e] + bb;
            }
        }
    }
}

// ---------------- GEMM 256x128, 8 waves, counted-vmcnt ring (gemm2) --------
// R11: proven (~20 us, 256 blocks = 1/CU, single round). FROZEN.
#define UBM 256
#define UBN 128
#define UBK 64

__global__ __launch_bounds__(512) void gemm_bt256x128(
    const __hip_bfloat16* __restrict__ A,
    const __hip_bfloat16* __restrict__ Bm,
    const float* __restrict__ bias,
    float* __restrict__ out, int N1, int K) {
    __shared__ alignas(16) __hip_bfloat16 sA[2 * UBM * UBK];  // 64 KiB
    __shared__ alignas(16) __hip_bfloat16 sB[2 * UBN * UBK];  // 32 KiB

    const int tid = threadIdx.x;
    const int lane = tid & 63;
    const int wid = tid >> 6;    // 0..7
    const int wrow = wid >> 2;   // 0..1 : M half (128 rows)
    const int wcol = wid & 3;    // 0..3 : N quarter (32 cols)

    const int lrow8 = lane >> 3;
    const int gchunk = (lane & 7) ^ lrow8;  // write-side chunk swizzle

    const int r16 = lane & 15;
    const int qd = lane >> 4;
    const int sw = r16 & 7;  // read-side swizzle key

    // grid 8 x 32 = 256 blocks; XCD-chunked swizzle (256 % 8 == 0, bijective)
    const int lin = blockIdx.x + (blockIdx.y << 3);
    const int swz = (lin & 7) * 32 + (lin >> 3);
    const int bx = swz & 7;
    const int by = swz >> 3;

    const size_t arow0 = (size_t)by * UBM;
    const size_t brow0 = (size_t)bx * UBN;

    const int nt = K >> 6;
    const size_t rowskip = (size_t)64 * K;

    const __hip_bfloat16* gA = A + (arow0 + wid * 8 + lrow8) * (size_t)K + gchunk * 8;
    const __hip_bfloat16* gB = Bm + (brow0 + wid * 8 + lrow8) * (size_t)K + gchunk * 8;
    const int ldsAb = wid * 8 * UBK;  // wave-uniform LDS base (elems)

    // 4 A-rounds (256 rows) + 2 B-rounds (128 rows) = 6 gloads per stage
    auto stage = [&](int cc, int ktn) {
#pragma unroll
        for (int rd = 0; rd < 4; ++rd)
            __builtin_amdgcn_global_load_lds(
                (const AS1 unsigned int*)(const void*)(gA + (size_t)rd * rowskip + ktn * UBK),
                (AS3 unsigned int*)(void*)(sA + cc * (UBM * UBK) + ldsAb + rd * (64 * UBK)),
                16, 0, 0);
#pragma unroll
        for (int rd = 0; rd < 2; ++rd)
            __builtin_amdgcn_global_load_lds(
                (const AS1 unsigned int*)(const void*)(gB + (size_t)rd * rowskip + ktn * UBK),
                (AS3 unsigned int*)(void*)(sB + cc * (UBN * UBK) + ldsAb + rd * (64 * UBK)),
                16, 0, 0);
    };

    floatx4 acc[8][2];
#pragma unroll
    for (int i = 0; i < 8; i++)
#pragma unroll
        for (int j = 0; j < 2; j++) acc[i][j] = (floatx4){0.f, 0.f, 0.f, 0.f};

    const int aofs = (wrow * 128 + r16) * UBK;
    const int bofs = (wcol * 32 + r16) * UBK;
    const int ck0 = ((qd ^ sw) * 8);
    const int ck1 = (((qd + 4) ^ sw) * 8);

    // prologue: stage K-tiles 0 and 1 (12 loads); wait tile 0 (<=6 left)
    stage(0, 0);
    stage(1, 1);
    asm volatile("s_waitcnt vmcnt(6)" ::: "memory");
    __builtin_amdgcn_s_barrier();

#pragma unroll 1
    for (int kt = 0; kt < nt; ++kt) {
        const int c = kt & 1;
        const __hip_bfloat16* sAc = sA + c * (UBM * UBK);
        const __hip_bfloat16* sBc = sB + c * (UBN * UBK);

        short8 afr[8][2], bfr[2][2];

        // ---- Phase A: ds_read bfr (4) + afr[0..3] (8); MFMA i0-1
#pragma unroll
        for (int f = 0; f < 2; ++f) {
            bfr[f][0] = *(const short8*)(sBc + bofs + f * 1024 + ck0);
            bfr[f][1] = *(const short8*)(sBc + bofs + f * 1024 + ck1);
        }
#pragma unroll
        for (int f = 0; f < 4; ++f) {
            afr[f][0] = *(const short8*)(sAc + aofs + f * 1024 + ck0);
            afr[f][1] = *(const short8*)(sAc + aofs + f * 1024 + ck1);
        }
        __builtin_amdgcn_s_setprio(1);
#pragma unroll
        for (int i = 0; i < 2; ++i)
#pragma unroll
            for (int j = 0; j < 2; ++j)
#pragma unroll
                for (int kk = 0; kk < 2; ++kk)
                    acc[i][j] = __builtin_amdgcn_mfma_f32_16x16x32_bf16(
                        afr[i][kk], bfr[j][kk], acc[i][j], 0, 0, 0);
        __builtin_amdgcn_s_setprio(0);

        // ---- Phase B: ds_read afr[4..7] (8); MFMA i2-3
#pragma unroll
        for (int f = 4; f < 8; ++f) {
            afr[f][0] = *(const short8*)(sAc + aofs + f * 1024 + ck0);
            afr[f][1] = *(const short8*)(sAc + aofs + f * 1024 + ck1);
        }
        __builtin_amdgcn_s_setprio(1);
#pragma unroll
        for (int i = 2; i < 4; ++i)
#pragma unroll
            for (int j = 0; j < 2; ++j)
#pragma unroll
                for (int kk = 0; kk < 2; ++kk)
                    acc[i][j] = __builtin_amdgcn_mfma_f32_16x16x32_bf16(
                        afr[i][kk], bfr[j][kk], acc[i][j], 0, 0, 0);
        __builtin_amdgcn_s_setprio(0);

        // ---- boundary 1: all reads of buf[c] complete across the block
        asm volatile("s_waitcnt lgkmcnt(0)" ::: "memory");
        __builtin_amdgcn_sched_barrier(0);
        __builtin_amdgcn_s_barrier();

        // stage kt+2 into buf[c] (now safe to overwrite)
        if (kt + 2 < nt) stage(c, kt + 2);

        // ---- Phase C: pure-register MFMA i4-5
        __builtin_amdgcn_s_setprio(1);
#pragma unroll
        for (int i = 4; i < 6; ++i)
#pragma unroll
            for (int j = 0; j < 2; ++j)
#pragma unroll
                for (int kk = 0; kk < 2; ++kk)
                    acc[i][j] = __builtin_amdgcn_mfma_f32_16x16x32_bf16(
                        afr[i][kk], bfr[j][kk], acc[i][j], 0, 0, 0);
        __builtin_amdgcn_s_setprio(0);

        // ---- Phase D: pure-register MFMA i6-7
        __builtin_amdgcn_s_setprio(1);
#pragma unroll
        for (int i = 6; i < 8; ++i)
#pragma unroll
            for (int j = 0; j < 2; ++j)
#pragma unroll
                for (int kk = 0; kk < 2; ++kk)
                    acc[i][j] = __builtin_amdgcn_mfma_f32_16x16x32_bf16(
                        afr[i][kk], bfr[j][kk], acc[i][j], 0, 0, 0);
        __builtin_amdgcn_s_setprio(0);

        // ---- boundary 2: kt+1's 6 loads landed; kt+2's 6 stay in flight
        if (kt + 2 < nt) {
            asm volatile("s_waitcnt vmcnt(6)" ::: "memory");
        } else if (kt + 1 < nt) {
            asm volatile("s_waitcnt vmcnt(0)" ::: "memory");
        }
        if (kt + 1 < nt) __builtin_amdgcn_s_barrier();
    }

    // ---- epilogue (proven C/D mapping, single output + bias)
#pragma unroll
    for (int i = 0; i < 8; i++) {
#pragma unroll
        for (int j = 0; j < 2; j++) {
            const int colb = (int)brow0 + wcol * 32 + j * 16 + r16;
            const float bb = bias[colb];
#pragma unroll
            for (int e = 0; e < 4; e++) {
                const size_t row = arow0 + wrow * 128 + i * 16 + qd * 4 + e;
                out[row * (size_t)N1 + colb] = acc[i][j][e] + bb;
            }
        }
    }
}

// ---------------- attention kernel (8 lanes / position, float8 per lane) ----
// R4: XCD-chunked swizzle. R7: gate fused, bf16 out (88 VGPR, NATURAL
// allocation only — R2/R9: forced bounds spill catastrophically). R10:
// wave-uniform tap skip. R12: near-offset k rows staged in LDS — the block's
// 10 taps with off <= 32 read k rows [nblk-32, nblk+32), i.e. the block's own
// neighborhood. One 17 KB stage (zero-filled below row 0; stride 68 floats to
// spread quad-banks) converts the dependence-critical k loads of those taps
// from ~200-400 cyc L2 to LDS. v loads stay global (latency non-critical).
// Numerically identical: zero rows -> dv = 0 exactly (same as clamped-row x0).

static constexpr int OFFS[21] = {1, 2, 3, 4, 6, 8, 12, 16, 24, 32, 48,
                                 64, 96, 128, 192, 256, 384, 512, 768, 1024, 1536};
static constexpr int U1J[21] = {0, 0, 0, 1, 1, 2, 2, 3, 3, 4, 4,
                                5, 5, 6, 6, 7, 7, 8, 8, 9, 9};
static constexpr int U1T[21] = {1, 2, 3, 2, 3, 2, 3, 2, 3, 2, 3,
                                2, 3, 2, 3, 2, 3, 2, 3, 2, 3};
// second user j (tau is always 1); -1 = none
static constexpr int U2J[21] = {-1, 1, -1, 2, -1, 3, -1, 4, -1, 5, -1,
                                6, -1, 7, -1, 8, -1, 9, -1, 10, -1};

#define KL_STRIDE 68  // floats; row shift = 68%32=4 dwords -> p spreads quads

static __device__ __forceinline__ float red8(float s) {
    // sum across each 8-lane group; all 8 lanes get the sum.
    int t;
    // quad_perm [1,0,3,2] : lane ^ 1
    t = __builtin_amdgcn_update_dpp(0, __builtin_bit_cast(int, s), 0xB1, 0xF, 0xF, true);
    s += __builtin_bit_cast(float, t);
    // quad_perm [2,3,0,1] : lane ^ 2
    t = __builtin_amdgcn_update_dpp(0, __builtin_bit_cast(int, s), 0x4E, 0xF, 0xF, true);
    s += __builtin_bit_cast(float, t);
    // row_half_mirror : lane i <-> 7-i (within 8-lane half-row)
    t = __builtin_amdgcn_update_dpp(0, __builtin_bit_cast(int, s), 0x141, 0xF, 0xF, true);
    s += __builtin_bit_cast(float, t);
    return s;
}

__global__ __launch_bounds__(256) void attn_kernel(
    const float* __restrict__ qkv,
    const float* __restrict__ scale_gain,       // [11,16]
    const float* __restrict__ W_qscale,         // [11,64]
    const float* __restrict__ identity_bypass,  // [16]
    const float* __restrict__ pos_bias,         // [44,16]
    const float* __restrict__ gate,             // [8192,1024] fp32 (pre-sigmoid)
    __hip_bfloat16* __restrict__ gated) {       // [8192,1024] bf16 out
    __shared__ float k_lds[64 * KL_STRIDE];  // 17 KiB: k rows [nblk-32, nblk+32)

    const int lane = threadIdx.x & 63;
    const int p = lane >> 3;   // position within wave, 0..7
    const int l = lane & 7;    // d-chunk (8 floats), 0..7

    // XCD-chunked swizzle: hw assigns block i -> XCD i%8; give XCD x the
    // contiguous strip range [x*512, (x+1)*512). 4096 % 8 == 0 -> bijective.
    const int wg = blockIdx.x;
    const int swg = (wg & 7) * 512 + (wg >> 3);

    const int flat = (swg * 4 + (threadIdx.x >> 6)) * 8;  // first n of wave
    const int nbase = flat & (PN - 1);
    const int n = nbase + p;
    const int h = (flat >> 11) & (PH - 1);
    const int b = flat >> 15;

    const size_t base_bn = (size_t)b * PN;
    const int col = h * PHD + l * 8;
    const int nblk = (swg * 32) & (PN - 1);  // block's first n (32-aligned)

    // ---- stage k rows [nblk-32, nblk+32) for this (b,h); zero-fill n<0.
    // 64 rows x 16 float4 = 1024 float4 over 256 threads = 4 each.
    {
        const int tid = threadIdx.x;
#pragma unroll
        for (int i = 0; i < 4; ++i) {
            const int f4 = tid + i * 256;   // 0..1023
            const int r = f4 >> 4;          // 0..63
            const int c4 = f4 & 15;         // 0..15
            const int gr = nblk - 32 + r;
            float4 val = {0.f, 0.f, 0.f, 0.f};
            if (gr >= 0)
                val = *(const float4*)(qkv + (base_bn + gr) * (3 * PD) + PD +
                                       h * PHD + c4 * 4);
            *(float4*)(&k_lds[r * KL_STRIDE + c4 * 4]) = val;
        }
    }
    __syncthreads();

    const float* qp = qkv + (base_bn + n) * (3 * PD) + col;
    const float4 qa = *(const float4*)qp;
    const float4 qb = *(const float4*)(qp + 4);
    const float4 k0a = *(const float4*)(qp + PD);
    const float4 k0b = *(const float4*)(qp + PD + 4);
    const float4 v0a = *(const float4*)(qp + 2 * PD);
    const float4 v0b = *(const float4*)(qp + 2 * PD + 4);

    auto dot8 = [](float4 a0, float4 a1, float4 b0, float4 b1) {
        float s = a0.x * b0.x;
        s = fmaf(a0.y, b0.y, s);
        s = fmaf(a0.z, b0.z, s);
        s = fmaf(a0.w, b0.w, s);
        s = fmaf(a1.x, b1.x, s);
        s = fmaf(a1.y, b1.y, s);
        s = fmaf(a1.z, b1.z, s);
        s = fmaf(a1.w, b1.w, s);
        return red8(s);
    };

    const float dot0 = dot8(qa, qb, k0a, k0b);  // k0 regs die here

    // gains = softmax(q @ W_qscale^T + scale_gain[:,h]) over 11 scales
    float g[NSC];
    float mx = -1e30f;
#pragma unroll
    for (int s = 0; s < NSC; s++) {
        const float* wp = W_qscale + s * PHD + l * 8;
        const float4 w0 = *(const float4*)wp;
        const float4 w1 = *(const float4*)(wp + 4);
        g[s] = dot8(qa, qb, w0, w1) + scale_gain[s * PH + h];
        mx = fmaxf(mx, g[s]);
    }
    float ssum = 0.f;
#pragma unroll
    for (int s = 0; s < NSC; s++) {
        g[s] = __expf(g[s] - mx);
        ssum += g[s];
    }
    const float inv = 1.f / ssum;
#pragma unroll
    for (int s = 0; s < NSC; s++) g[s] *= inv;

    const float D4c[4] = {0.4829629131445341f, 0.8365163037378079f,
                          0.2241438680420134f, -0.1294095225512604f};

    float4 o0, o1;
    float z;

    // ---- offset-0 block: 11 tau=0 taps + identity bypass, all scale v0.
    {
        const float bp = log1pf(__expf(identity_bypass[h]));  // softplus
        const float f0 = (dot0 > 0.f ? dot0 : __expf(dot0) - 1.f) + 1.f;
        float wsum = bp * f0;
#pragma unroll
        for (int j = 0; j < NSC; j++) {
            const float xx = dot0 + pos_bias[(j * 4) * PH + h];
            const float feat = (xx > 0.f ? xx : __expf(xx) - 1.f) + 1.f;
            wsum = fmaf(g[j], D4c[0] * feat, wsum);
        }
        z = wsum;
        o0.x = wsum * v0a.x;
        o0.y = wsum * v0a.y;
        o0.z = wsum * v0a.z;
        o0.w = wsum * v0a.w;
        o1.x = wsum * v0b.x;
        o1.y = wsum * v0b.y;
        o1.z = wsum * v0b.z;
        o1.w = wsum * v0b.w;
    }  // v0 regs die here

    // ---- distinct nonzero offsets (each used by 1-2 taps, sharing k/v rows)
#pragma unroll
    for (int t = 0; t < 21; t++) {
        const int off = OFFS[t];
        if (off > nbase + 7) {
            // whole wave padded: dv == 0 exactly -> only z accumulates
            {
                const int j = U1J[t], tau = U1T[t];
                const float xx = pos_bias[(j * 4 + tau) * PH + h];
                const float feat = (xx > 0.f ? xx : __expf(xx) - 1.f) + 1.f;
                z = fmaf(g[j] * fabsf(D4c[tau]), feat, z);
            }
            if (U2J[t] >= 0) {
                const int j = U2J[t];
                const float xx = pos_bias[(j * 4 + 1) * PH + h];
                const float feat = (xx > 0.f ? xx : __expf(xx) - 1.f) + 1.f;
                z = fmaf(g[j] * D4c[1], feat, z);
            }
        } else {
            const bool valid = (n >= off);
            const int idx = valid ? (n - off) : 0;
            const float vm = valid ? 1.f : 0.f;
            const size_t rb = (base_bn + idx) * (3 * PD);
            float4 k4a, k4b;
            if (off <= 32) {
                // LDS path: lidx = (n - off) - (nblk - 32) in [0,63];
                // zero-filled rows give dot == 0 exactly for padded positions.
                const float* kl =
                    k_lds + ((n & 31) + 32 - off) * KL_STRIDE + l * 8;
                k4a = *(const float4*)kl;
                k4b = *(const float4*)(kl + 4);
            } else {
                const float* kp = qkv + rb + PD + col;
                k4a = *(const float4*)kp;
                k4b = *(const float4*)(kp + 4);
            }
            const float* vp = qkv + rb + 2 * PD + col;
            const float4 v4a = *(const float4*)vp;
            const float4 v4b = *(const float4*)(vp + 4);
            const float dv = dot8(qa, qb, k4a, k4b) * vm;

            // user 1: (U1J[t], U1T[t])
            float wv, zacc;
            {
                const int j = U1J[t], tau = U1T[t];
                const float xx = dv + pos_bias[(j * 4 + tau) * PH + h];
                const float feat = (xx > 0.f ? xx : __expf(xx) - 1.f) + 1.f;
                const float wp = g[j] * (D4c[tau] * feat);
                zacc = fabsf(wp);  // = g * |coef| * feat  (g,feat >= 0)
                wv = wp;
            }
            // user 2: (U2J[t], tau=1) if present
            if (U2J[t] >= 0) {
                const int j = U2J[t];
                const float xx = dv + pos_bias[(j * 4 + 1) * PH + h];
                const float feat = (xx > 0.f ? xx : __expf(xx) - 1.f) + 1.f;
                const float wp = g[j] * (D4c[1] * feat);
                zacc += wp;  // coef > 0
                wv += wp;
            }
            z += zacc;
            wv *= vm;
            o0.x = fmaf(wv, v4a.x, o0.x);
            o0.y = fmaf(wv, v4a.y, o0.y);
            o0.z = fmaf(wv, v4a.z, o0.z);
            o0.w = fmaf(wv, v4a.w, o0.w);
            o1.x = fmaf(wv, v4b.x, o1.x);
            o1.y = fmaf(wv, v4b.y, o1.y);
            o1.z = fmaf(wv, v4b.z, o1.z);
            o1.w = fmaf(wv, v4b.w, o1.w);
        }
    }

    // ---- tail: normalize, gate (sigmoid), emit bf16
    const float* gp2 = gate + (base_bn + n) * PD + col;
    const float4 ga = *(const float4*)gp2;
    const float4 gb = *(const float4*)(gp2 + 4);
    const float zi = 1.f / (z + 1e-6f);

    short8 r;
    r[0] = (short)bf16bits(o0.x * zi / (1.f + __expf(-ga.x)));
    r[1] = (short)bf16bits(o0.y * zi / (1.f + __expf(-ga.y)));
    r[2] = (short)bf16bits(o0.z * zi / (1.f + __expf(-ga.z)));
    r[3] = (short)bf16bits(o0.w * zi / (1.f + __expf(-ga.w)));
    r[4] = (short)bf16bits(o1.x * zi / (1.f + __expf(-gb.x)));
    r[5] = (short)bf16bits(o1.y * zi / (1.f + __expf(-gb.y)));
    r[6] = (short)bf16bits(o1.z * zi / (1.f + __expf(-gb.z)));
    r[7] = (short)bf16bits(o1.w * zi / (1.f + __expf(-gb.w)));
    *(short8*)(gated + (base_bn + n) * PD + col) = r;
}

// ---------------- launch ----------------
extern "C" void kernel_launch(void* const* d_in, const int* in_sizes, int n_in,
                              void* d_out, int out_size, void* d_ws, size_t ws_size,
                              hipStream_t stream) {
    const float* x = (const float*)d_in[0];
    const float* W_qkv = (const float*)d_in[1];
    const float* b_qkv = (const float*)d_in[2];
    const float* W_out = (const float*)d_in[3];
    const float* b_out = (const float*)d_in[4];
    const float* W_gate = (const float*)d_in[5];
    const float* b_gate = (const float*)d_in[6];
    const float* scale_gain = (const float*)d_in[7];
    const float* W_qscale = (const float*)d_in[8];
    const float* identity_bypass = (const float*)d_in[9];
    const float* pos_bias = (const float*)d_in[10];
    float* out = (float*)d_out;

    const int M = PB * PN;  // 8192
    char* ws = (char*)d_ws;
    size_t off = 0;
    auto alloc = [&](size_t bytes) -> void* {
        void* p = ws + off;
        off += (bytes + 255) & ~(size_t)255;
        return p;
    };
    __hip_bfloat16* x_bf = (__hip_bfloat16*)alloc((size_t)M * PD * 2);
    __hip_bfloat16* wcomb_bf = (__hip_bfloat16*)alloc((size_t)4 * PD * PD * 2);
    __hip_bfloat16* wout_bf = (__hip_bfloat16*)alloc((size_t)PD * PD * 2);
    float* qkv = (float*)alloc((size_t)M * 3 * PD * 4);
    float* gate = (float*)alloc((size_t)M * PD * 4);
    __hip_bfloat16* gated = (__hip_bfloat16*)alloc((size_t)M * PD * 2);

    // merged casts: x -> bf16, weights -> bf16 (one dispatch)
    const int TOT4 = M * PD / 4 + 5 * PD * PD / 4;
    cast_all<<<TOT4 / 256, 256, 0, stream>>>(
        (const float4*)x, (const float4*)W_qkv, (const float4*)W_gate,
        (const float4*)W_out, (ushort4*)x_bf, (ushort4*)wcomb_bf,
        (ushort4*)wout_bf);

    // {qkv, gate} = x @ [W_qkv; W_gate]^T + {b_qkv, b_gate}  (256² pipeline)
    gemm_bt256<<<dim3(4 * PD / TBN, M / TBM), 512, 0, stream>>>(
        x_bf, wcomb_bf, b_qkv, b_gate, 3 * PD, qkv, 3 * PD, gate, PD, PD);

    // attention + gate + bf16 emit -> gated [8192,1024] bf16
    attn_kernel<<<(PB * PH * PN) / 32, 256, 0, stream>>>(
        qkv, scale_gain, W_qscale, identity_bypass, pos_bias, gate, gated);

    // out = gated @ W_out^T + b_out  (256x128 ring, 256 blocks = 1/CU, 1 round)
    gemm_bt256x128<<<dim3(PD / UBN, M / UBM), 512, 0, stream>>>(
        gated, wout_bf, b_out, out, PD, PD);
}

// Round 13
// 273.186 us; speedup vs baseline: 1.8197x; 1.0149x over previous
//
#include <hip/hip_runtime.h>
#include <hip/hip_bf16.h>

// Problem constants
#define PB 4
#define PN 2048
#define PD 1024
#define PH 16
#define PHD 64
#define NSC 11

typedef __attribute__((ext_vector_type(8))) short short8;
typedef __attribute__((ext_vector_type(4))) float floatx4;

#define AS1 __attribute__((address_space(1)))
#define AS3 __attribute__((address_space(3)))

static __device__ __forceinline__ unsigned short bf16bits(float f) {
    __hip_bfloat16 h = __float2bfloat16(f);
    return __builtin_bit_cast(unsigned short, h);
}

// ---------------- merged cast kernel (one launch) ----------------
// x (8M floats) -> x_bf ; W_qkv(3M)+W_gate(1M) -> wcomb ; W_out(1M) -> woutb
__global__ void cast_all(const float4* __restrict__ x,
                         const float4* __restrict__ wqkv,
                         const float4* __restrict__ wgate,
                         const float4* __restrict__ wout,
                         ushort4* __restrict__ x_bf,
                         ushort4* __restrict__ wcomb,
                         ushort4* __restrict__ woutb) {
    int i = blockIdx.x * blockDim.x + threadIdx.x;
    const int X4 = PB * PN * PD / 4;
    const int QKV4 = 3 * PD * PD / 4;
    const int G4 = PD * PD / 4;
    float4 v;
    ushort4* dst;
    if (i < X4) {
        v = x[i];
        dst = x_bf + i;
    } else {
        int j = i - X4;
        if (j < QKV4) {
            v = wqkv[j];
            dst = wcomb + j;
        } else if (j < QKV4 + G4) {
            v = wgate[j - QKV4];
            dst = wcomb + j;
        } else {
            v = wout[j - QKV4 - G4];
            dst = woutb + (j - QKV4 - G4);
        }
    }
    ushort4 o;
    o.x = bf16bits(v.x);
    o.y = bf16bits(v.y);
    o.z = bf16bits(v.z);
    o.w = bf16bits(v.w);
    *dst = o;
}

// ---------------- GEMM 256x256, 8 waves, counted-vmcnt schedule (gemm1) ----
// R5 structure (proven). R6's finer 4-phase barrier graft REGRESSED — R5
// schedule kept verbatim. R10: XCD-chunked block swizzle (A panels XCD-local).
// R13: gate output (columns >= split) now emitted as bf16 — halves the gate
// write (and attn's gate read). Branch is block-uniform (brow0 256-aligned,
// split 3072).
#define TBM 256
#define TBN 256
#define TBK 64

__global__ __launch_bounds__(512) void gemm_bt256(
    const __hip_bfloat16* __restrict__ A,
    const __hip_bfloat16* __restrict__ Bm,
    const float* __restrict__ b1,
    const float* __restrict__ b2,
    int split,
    float* __restrict__ out1, int N1,
    __hip_bfloat16* __restrict__ out2, int N2,
    int K) {
    __shared__ alignas(16) __hip_bfloat16 sA[2 * TBM * TBK];  // 64 KiB
    __shared__ alignas(16) __hip_bfloat16 sB[2 * TBN * TBK];  // 64 KiB

    const int tid = threadIdx.x;
    const int lane = tid & 63;
    const int wid = tid >> 6;    // 0..7
    const int wrow = wid >> 2;   // 0..1 : M half (128 rows)
    const int wcol = wid & 3;    // 0..3 : N quarter (64 cols)

    const int lrow8 = lane >> 3;
    const int lchunk = lane & 7;
    const int gchunk = lchunk ^ lrow8;  // write-side chunk swizzle

    const int r16 = lane & 15;
    const int qd = lane >> 4;
    const int sw = r16 & 7;  // read-side swizzle key

    // XCD-chunked swizzle (grid is fixed 16 x 32 = 512 blocks for gemm1):
    // lin%8 = XCD; give XCD k the contiguous lin-range [k*64,(k+1)*64).
    const int lin = blockIdx.x + (blockIdx.y << 4);
    const int swz = (lin & 7) * 64 + (lin >> 3);
    const int bx = swz & 15;
    const int by = swz >> 4;

    const size_t arow0 = (size_t)by * TBM;
    const size_t brow0 = (size_t)bx * TBN;

    const int nt = K >> 6;  // K-tiles
    const size_t rowskip = (size_t)64 * K;

    const __hip_bfloat16* gA = A + (arow0 + wid * 8 + lrow8) * (size_t)K + gchunk * 8;
    const __hip_bfloat16* gB = Bm + (brow0 + wid * 8 + lrow8) * (size_t)K + gchunk * 8;
    const int ldsAb = wid * 8 * TBK;  // wave-uniform LDS base (elems)

    auto stage = [&](int cc, int ktn) {
#pragma unroll
        for (int rd = 0; rd < 4; ++rd) {
            __builtin_amdgcn_global_load_lds(
                (const AS1 unsigned int*)(const void*)(gA + (size_t)rd * rowskip + ktn * TBK),
                (AS3 unsigned int*)(void*)(sA + cc * (TBM * TBK) + ldsAb + rd * (64 * TBK)),
                16, 0, 0);
            __builtin_amdgcn_global_load_lds(
                (const AS1 unsigned int*)(const void*)(gB + (size_t)rd * rowskip + ktn * TBK),
                (AS3 unsigned int*)(void*)(sB + cc * (TBN * TBK) + ldsAb + rd * (64 * TBK)),
                16, 0, 0);
        }
    };

    floatx4 acc[8][4];
#pragma unroll
    for (int i = 0; i < 8; i++)
#pragma unroll
        for (int j = 0; j < 4; j++) acc[i][j] = (floatx4){0.f, 0.f, 0.f, 0.f};

    const int aofs = (wrow * 128 + r16) * TBK;
    const int bofs = (wcol * 64 + r16) * TBK;
    const int ck0 = ((qd ^ sw) * 8);
    const int ck1 = (((qd + 4) ^ sw) * 8);

    // prologue: stage K-tiles 0 and 1
    stage(0, 0);
    stage(1, 1);
    asm volatile("s_waitcnt vmcnt(8)" ::: "memory");  // K-tile 0 landed
    __builtin_amdgcn_s_barrier();

#pragma unroll 1
    for (int kt = 0; kt < nt; ++kt) {
        const int c = kt & 1;
        const __hip_bfloat16* sAc = sA + c * (TBM * TBK);
        const __hip_bfloat16* sBc = sB + c * (TBN * TBK);

        short8 afr[8][2], bfr[4][2];

        // ---- Phase A: ds_read af rh0 (rf0-3) + bf ch0 (cf0-1); MFMA Q0
#pragma unroll
        for (int f = 0; f < 2; ++f) {
            bfr[f][0] = *(const short8*)(sBc + bofs + f * 1024 + ck0);
            bfr[f][1] = *(const short8*)(sBc + bofs + f * 1024 + ck1);
        }
#pragma unroll
        for (int f = 0; f < 4; ++f) {
            afr[f][0] = *(const short8*)(sAc + aofs + f * 1024 + ck0);
            afr[f][1] = *(const short8*)(sAc + aofs + f * 1024 + ck1);
        }
        __builtin_amdgcn_s_setprio(1);
#pragma unroll
        for (int i = 0; i < 4; ++i)
#pragma unroll
            for (int j = 0; j < 2; ++j)
#pragma unroll
                for (int kk = 0; kk < 2; ++kk)
                    acc[i][j] = __builtin_amdgcn_mfma_f32_16x16x32_bf16(
                        afr[i][kk], bfr[j][kk], acc[i][j], 0, 0, 0);
        __builtin_amdgcn_s_setprio(0);

        // ---- Phase B: ds_read bf ch1 (cf2-3) + af rh1 (rf4-7); MFMA Q1
#pragma unroll
        for (int f = 2; f < 4; ++f) {
            bfr[f][0] = *(const short8*)(sBc + bofs + f * 1024 + ck0);
            bfr[f][1] = *(const short8*)(sBc + bofs + f * 1024 + ck1);
        }
#pragma unroll
        for (int f = 4; f < 8; ++f) {
            afr[f][0] = *(const short8*)(sAc + aofs + f * 1024 + ck0);
            afr[f][1] = *(const short8*)(sAc + aofs + f * 1024 + ck1);
        }
        __builtin_amdgcn_s_setprio(1);
#pragma unroll
        for (int i = 0; i < 4; ++i)
#pragma unroll
            for (int j = 2; j < 4; ++j)
#pragma unroll
            for (int kk = 0; kk < 2; ++kk)
                    acc[i][j] = __builtin_amdgcn_mfma_f32_16x16x32_bf16(
                        afr[i][kk], bfr[j][kk], acc[i][j], 0, 0, 0);
        __builtin_amdgcn_s_setprio(0);

        // ---- boundary 1: all reads of buf[c] complete across the block
        asm volatile("s_waitcnt lgkmcnt(0)" ::: "memory");
        __builtin_amdgcn_sched_barrier(0);
        __builtin_amdgcn_s_barrier();

        // stage kt+2 into buf[c] (now safe to overwrite)
        if (kt + 2 < nt) stage(c, kt + 2);

        // ---- Phase C: pure-register MFMA Q2 (rf4-7 x cf0-1)
        __builtin_amdgcn_s_setprio(1);
#pragma unroll
        for (int i = 4; i < 8; ++i)
#pragma unroll
            for (int j = 0; j < 2; ++j)
#pragma unroll
                for (int kk = 0; kk < 2; ++kk)
                    acc[i][j] = __builtin_amdgcn_mfma_f32_16x16x32_bf16(
                        afr[i][kk], bfr[j][kk], acc[i][j], 0, 0, 0);
        __builtin_amdgcn_s_setprio(0);

        // ---- Phase D: pure-register MFMA Q3 (rf4-7 x cf2-3)
        __builtin_amdgcn_s_setprio(1);
#pragma unroll
        for (int i = 4; i < 8; ++i)
#pragma unroll
            for (int j = 2; j < 4; ++j)
#pragma unroll
                for (int kk = 0; kk < 2; ++kk)
                    acc[i][j] = __builtin_amdgcn_mfma_f32_16x16x32_bf16(
                        afr[i][kk], bfr[j][kk], acc[i][j], 0, 0, 0);
        __builtin_amdgcn_s_setprio(0);

        // ---- boundary 2: kt+1's data landed; kt+2's loads stay in flight
        if (kt + 2 < nt) {
            asm volatile("s_waitcnt vmcnt(8)" ::: "memory");
        } else if (kt + 1 < nt) {
            asm volatile("s_waitcnt vmcnt(0)" ::: "memory");
        }
        if (kt + 1 < nt) __builtin_amdgcn_s_barrier();
    }

    // ---- epilogue (proven C/D mapping; fp32 to out1, bf16 to out2)
    const bool first = (int)brow0 < split;  // block-uniform (brow0 256-aligned)
#pragma unroll
    for (int i = 0; i < 8; i++) {
#pragma unroll
        for (int j = 0; j < 4; j++) {
            const int colb = (int)brow0 + wcol * 64 + j * 16 + r16;
            if (first) {
                const float bb = b1[colb];
#pragma unroll
                for (int e = 0; e < 4; e++) {
                    const size_t row = arow0 + wrow * 128 + i * 16 + qd * 4 + e;
                    out1[row * (size_t)N1 + colb] = acc[i][j][e] + bb;
                }
            } else {
                const int cc = colb - split;
                const float bb = b2[cc];
#pragma unroll
                for (int e = 0; e < 4; e++) {
                    const size_t row = arow0 + wrow * 128 + i * 16 + qd * 4 + e;
                    out2[row * (size_t)N2 + cc] = __float2bfloat16(acc[i][j][e] + bb);
                }
            }
        }
    }
}

// ---------------- GEMM 256x128, 8 waves, counted-vmcnt ring (gemm2) --------
// R11: proven (~20 us, 256 blocks = 1/CU, single round). FROZEN.
#define UBM 256
#define UBN 128
#define UBK 64

__global__ __launch_bounds__(512) void gemm_bt256x128(
    const __hip_bfloat16* __restrict__ A,
    const __hip_bfloat16* __restrict__ Bm,
    const float* __restrict__ bias,
    float* __restrict__ out, int N1, int K) {
    __shared__ alignas(16) __hip_bfloat16 sA[2 * UBM * UBK];  // 64 KiB
    __shared__ alignas(16) __hip_bfloat16 sB[2 * UBN * UBK];  // 32 KiB

    const int tid = threadIdx.x;
    const int lane = tid & 63;
    const int wid = tid >> 6;    // 0..7
    const int wrow = wid >> 2;   // 0..1 : M half (128 rows)
    const int wcol = wid & 3;    // 0..3 : N quarter (32 cols)

    const int lrow8 = lane >> 3;
    const int gchunk = (lane & 7) ^ lrow8;  // write-side chunk swizzle

    const int r16 = lane & 15;
    const int qd = lane >> 4;
    const int sw = r16 & 7;  // read-side swizzle key

    // grid 8 x 32 = 256 blocks; XCD-chunked swizzle (256 % 8 == 0, bijective)
    const int lin = blockIdx.x + (blockIdx.y << 3);
    const int swz = (lin & 7) * 32 + (lin >> 3);
    const int bx = swz & 7;
    const int by = swz >> 3;

    const size_t arow0 = (size_t)by * UBM;
    const size_t brow0 = (size_t)bx * UBN;

    const int nt = K >> 6;
    const size_t rowskip = (size_t)64 * K;

    const __hip_bfloat16* gA = A + (arow0 + wid * 8 + lrow8) * (size_t)K + gchunk * 8;
    const __hip_bfloat16* gB = Bm + (brow0 + wid * 8 + lrow8) * (size_t)K + gchunk * 8;
    const int ldsAb = wid * 8 * UBK;  // wave-uniform LDS base (elems)

    // 4 A-rounds (256 rows) + 2 B-rounds (128 rows) = 6 gloads per stage
    auto stage = [&](int cc, int ktn) {
#pragma unroll
        for (int rd = 0; rd < 4; ++rd)
            __builtin_amdgcn_global_load_lds(
                (const AS1 unsigned int*)(const void*)(gA + (size_t)rd * rowskip + ktn * UBK),
                (AS3 unsigned int*)(void*)(sA + cc * (UBM * UBK) + ldsAb + rd * (64 * UBK)),
                16, 0, 0);
#pragma unroll
        for (int rd = 0; rd < 2; ++rd)
            __builtin_amdgcn_global_load_lds(
                (const AS1 unsigned int*)(const void*)(gB + (size_t)rd * rowskip + ktn * UBK),
                (AS3 unsigned int*)(void*)(sB + cc * (UBN * UBK) + ldsAb + rd * (64 * UBK)),
                16, 0, 0);
    };

    floatx4 acc[8][2];
#pragma unroll
    for (int i = 0; i < 8; i++)
#pragma unroll
        for (int j = 0; j < 2; j++) acc[i][j] = (floatx4){0.f, 0.f, 0.f, 0.f};

    const int aofs = (wrow * 128 + r16) * UBK;
    const int bofs = (wcol * 32 + r16) * UBK;
    const int ck0 = ((qd ^ sw) * 8);
    const int ck1 = (((qd + 4) ^ sw) * 8);

    // prologue: stage K-tiles 0 and 1 (12 loads); wait tile 0 (<=6 left)
    stage(0, 0);
    stage(1, 1);
    asm volatile("s_waitcnt vmcnt(6)" ::: "memory");
    __builtin_amdgcn_s_barrier();

#pragma unroll 1
    for (int kt = 0; kt < nt; ++kt) {
        const int c = kt & 1;
        const __hip_bfloat16* sAc = sA + c * (UBM * UBK);
        const __hip_bfloat16* sBc = sB + c * (UBN * UBK);

        short8 afr[8][2], bfr[2][2];

        // ---- Phase A: ds_read bfr (4) + afr[0..3] (8); MFMA i0-1
#pragma unroll
        for (int f = 0; f < 2; ++f) {
            bfr[f][0] = *(const short8*)(sBc + bofs + f * 1024 + ck0);
            bfr[f][1] = *(const short8*)(sBc + bofs + f * 1024 + ck1);
        }
#pragma unroll
        for (int f = 0; f < 4; ++f) {
            afr[f][0] = *(const short8*)(sAc + aofs + f * 1024 + ck0);
            afr[f][1] = *(const short8*)(sAc + aofs + f * 1024 + ck1);
        }
        __builtin_amdgcn_s_setprio(1);
#pragma unroll
        for (int i = 0; i < 2; ++i)
#pragma unroll
            for (int j = 0; j < 2; ++j)
#pragma unroll
                for (int kk = 0; kk < 2; ++kk)
                    acc[i][j] = __builtin_amdgcn_mfma_f32_16x16x32_bf16(
                        afr[i][kk], bfr[j][kk], acc[i][j], 0, 0, 0);
        __builtin_amdgcn_s_setprio(0);

        // ---- Phase B: ds_read afr[4..7] (8); MFMA i2-3
#pragma unroll
        for (int f = 4; f < 8; ++f) {
            afr[f][0] = *(const short8*)(sAc + aofs + f * 1024 + ck0);
            afr[f][1] = *(const short8*)(sAc + aofs + f * 1024 + ck1);
        }
        __builtin_amdgcn_s_setprio(1);
#pragma unroll
        for (int i = 2; i < 4; ++i)
#pragma unroll
            for (int j = 0; j < 2; ++j)
#pragma unroll
                for (int kk = 0; kk < 2; ++kk)
                    acc[i][j] = __builtin_amdgcn_mfma_f32_16x16x32_bf16(
                        afr[i][kk], bfr[j][kk], acc[i][j], 0, 0, 0);
        __builtin_amdgcn_s_setprio(0);

        // ---- boundary 1: all reads of buf[c] complete across the block
        asm volatile("s_waitcnt lgkmcnt(0)" ::: "memory");
        __builtin_amdgcn_sched_barrier(0);
        __builtin_amdgcn_s_barrier();

        // stage kt+2 into buf[c] (now safe to overwrite)
        if (kt + 2 < nt) stage(c, kt + 2);

        // ---- Phase C: pure-register MFMA i4-5
        __builtin_amdgcn_s_setprio(1);
#pragma unroll
        for (int i = 4; i < 6; ++i)
#pragma unroll
            for (int j = 0; j < 2; ++j)
#pragma unroll
                for (int kk = 0; kk < 2; ++kk)
                    acc[i][j] = __builtin_amdgcn_mfma_f32_16x16x32_bf16(
                        afr[i][kk], bfr[j][kk], acc[i][j], 0, 0, 0);
        __builtin_amdgcn_s_setprio(0);

        // ---- Phase D: pure-register MFMA i6-7
        __builtin_amdgcn_s_setprio(1);
#pragma unroll
        for (int i = 6; i < 8; ++i)
#pragma unroll
            for (int j = 0; j < 2; ++j)
#pragma unroll
                for (int kk = 0; kk < 2; ++kk)
                    acc[i][j] = __builtin_amdgcn_mfma_f32_16x16x32_bf16(
                        afr[i][kk], bfr[j][kk], acc[i][j], 0, 0, 0);
        __builtin_amdgcn_s_setprio(0);

        // ---- boundary 2: kt+1's 6 loads landed; kt+2's 6 stay in flight
        if (kt + 2 < nt) {
            asm volatile("s_waitcnt vmcnt(6)" ::: "memory");
        } else if (kt + 1 < nt) {
            asm volatile("s_waitcnt vmcnt(0)" ::: "memory");
        }
        if (kt + 1 < nt) __builtin_amdgcn_s_barrier();
    }

    // ---- epilogue (proven C/D mapping, single output + bias)
#pragma unroll
    for (int i = 0; i < 8; i++) {
#pragma unroll
        for (int j = 0; j < 2; j++) {
            const int colb = (int)brow0 + wcol * 32 + j * 16 + r16;
            const float bb = bias[colb];
#pragma unroll
            for (int e = 0; e < 4; e++) {
                const size_t row = arow0 + wrow * 128 + i * 16 + qd * 4 + e;
                out[row * (size_t)N1 + colb] = acc[i][j][e] + bb;
            }
        }
    }
}

// ---------------- attention kernel (8 lanes / position, float8 per lane) ----
// R4: XCD-chunked swizzle. R7: gate fused, bf16 out (NATURAL allocation only
// — R2/R9: forced bounds spill catastrophically). R10: wave-uniform tap skip.
// R12: near-offset k rows staged in LDS (off <= 32 served from a 17 KB tile).
// R13: gate arrives as bf16 (half the tail read).

static constexpr int OFFS[21] = {1, 2, 3, 4, 6, 8, 12, 16, 24, 32, 48,
                                 64, 96, 128, 192, 256, 384, 512, 768, 1024, 1536};
static constexpr int U1J[21] = {0, 0, 0, 1, 1, 2, 2, 3, 3, 4, 4,
                                5, 5, 6, 6, 7, 7, 8, 8, 9, 9};
static constexpr int U1T[21] = {1, 2, 3, 2, 3, 2, 3, 2, 3, 2, 3,
                                2, 3, 2, 3, 2, 3, 2, 3, 2, 3};
// second user j (tau is always 1); -1 = none
static constexpr int U2J[21] = {-1, 1, -1, 2, -1, 3, -1, 4, -1, 5, -1,
                                6, -1, 7, -1, 8, -1, 9, -1, 10, -1};

#define KL_STRIDE 68  // floats; row shift = 68%32=4 dwords -> p spreads quads

static __device__ __forceinline__ float red8(float s) {
    // sum across each 8-lane group; all 8 lanes get the sum.
    int t;
    // quad_perm [1,0,3,2] : lane ^ 1
    t = __builtin_amdgcn_update_dpp(0, __builtin_bit_cast(int, s), 0xB1, 0xF, 0xF, true);
    s += __builtin_bit_cast(float, t);
    // quad_perm [2,3,0,1] : lane ^ 2
    t = __builtin_amdgcn_update_dpp(0, __builtin_bit_cast(int, s), 0x4E, 0xF, 0xF, true);
    s += __builtin_bit_cast(float, t);
    // row_half_mirror : lane i <-> 7-i (within 8-lane half-row)
    t = __builtin_amdgcn_update_dpp(0, __builtin_bit_cast(int, s), 0x141, 0xF, 0xF, true);
    s += __builtin_bit_cast(float, t);
    return s;
}

__global__ __launch_bounds__(256) void attn_kernel(
    const float* __restrict__ qkv,
    const float* __restrict__ scale_gain,       // [11,16]
    const float* __restrict__ W_qscale,         // [11,64]
    const float* __restrict__ identity_bypass,  // [16]
    const float* __restrict__ pos_bias,         // [44,16]
    const __hip_bfloat16* __restrict__ gate,    // [8192,1024] bf16 (pre-sigmoid)
    __hip_bfloat16* __restrict__ gated) {       // [8192,1024] bf16 out
    __shared__ float k_lds[64 * KL_STRIDE];  // 17 KiB: k rows [nblk-32, nblk+32)

    const int lane = threadIdx.x & 63;
    const int p = lane >> 3;   // position within wave, 0..7
    const int l = lane & 7;    // d-chunk (8 floats), 0..7

    // XCD-chunked swizzle: hw assigns block i -> XCD i%8; give XCD x the
    // contiguous strip range [x*512, (x+1)*512). 4096 % 8 == 0 -> bijective.
    const int wg = blockIdx.x;
    const int swg = (wg & 7) * 512 + (wg >> 3);

    const int flat = (swg * 4 + (threadIdx.x >> 6)) * 8;  // first n of wave
    const int nbase = flat & (PN - 1);
    const int n = nbase + p;
    const int h = (flat >> 11) & (PH - 1);
    const int b = flat >> 15;

    const size_t base_bn = (size_t)b * PN;
    const int col = h * PHD + l * 8;
    const int nblk = (swg * 32) & (PN - 1);  // block's first n (32-aligned)

    // ---- stage k rows [nblk-32, nblk+32) for this (b,h); zero-fill n<0.
    // 64 rows x 16 float4 = 1024 float4 over 256 threads = 4 each.
    {
        const int tid = threadIdx.x;
#pragma unroll
        for (int i = 0; i < 4; ++i) {
            const int f4 = tid + i * 256;   // 0..1023
            const int r = f4 >> 4;          // 0..63
            const int c4 = f4 & 15;         // 0..15
            const int gr = nblk - 32 + r;
            float4 val = {0.f, 0.f, 0.f, 0.f};
            if (gr >= 0)
                val = *(const float4*)(qkv + (base_bn + gr) * (3 * PD) + PD +
                                       h * PHD + c4 * 4);
            *(float4*)(&k_lds[r * KL_STRIDE + c4 * 4]) = val;
        }
    }
    __syncthreads();

    const float* qp = qkv + (base_bn + n) * (3 * PD) + col;
    const float4 qa = *(const float4*)qp;
    const float4 qb = *(const float4*)(qp + 4);
    const float4 k0a = *(const float4*)(qp + PD);
    const float4 k0b = *(const float4*)(qp + PD + 4);
    const float4 v0a = *(const float4*)(qp + 2 * PD);
    const float4 v0b = *(const float4*)(qp + 2 * PD + 4);

    auto dot8 = [](float4 a0, float4 a1, float4 b0, float4 b1) {
        float s = a0.x * b0.x;
        s = fmaf(a0.y, b0.y, s);
        s = fmaf(a0.z, b0.z, s);
        s = fmaf(a0.w, b0.w, s);
        s = fmaf(a1.x, b1.x, s);
        s = fmaf(a1.y, b1.y, s);
        s = fmaf(a1.z, b1.z, s);
        s = fmaf(a1.w, b1.w, s);
        return red8(s);
    };

    const float dot0 = dot8(qa, qb, k0a, k0b);  // k0 regs die here

    // gains = softmax(q @ W_qscale^T + scale_gain[:,h]) over 11 scales
    float g[NSC];
    float mx = -1e30f;
#pragma unroll
    for (int s = 0; s < NSC; s++) {
        const float* wp = W_qscale + s * PHD + l * 8;
        const float4 w0 = *(const float4*)wp;
        const float4 w1 = *(const float4*)(wp + 4);
        g[s] = dot8(qa, qb, w0, w1) + scale_gain[s * PH + h];
        mx = fmaxf(mx, g[s]);
    }
    float ssum = 0.f;
#pragma unroll
    for (int s = 0; s < NSC; s++) {
        g[s] = __expf(g[s] - mx);
        ssum += g[s];
    }
    const float inv = 1.f / ssum;
#pragma unroll
    for (int s = 0; s < NSC; s++) g[s] *= inv;

    const float D4c[4] = {0.4829629131445341f, 0.8365163037378079f,
                          0.2241438680420134f, -0.1294095225512604f};

    float4 o0, o1;
    float z;

    // ---- offset-0 block: 11 tau=0 taps + identity bypass, all scale v0.
    {
        const float bp = log1pf(__expf(identity_bypass[h]));  // softplus
        const float f0 = (dot0 > 0.f ? dot0 : __expf(dot0) - 1.f) + 1.f;
        float wsum = bp * f0;
#pragma unroll
        for (int j = 0; j < NSC; j++) {
            const float xx = dot0 + pos_bias[(j * 4) * PH + h];
            const float feat = (xx > 0.f ? xx : __expf(xx) - 1.f) + 1.f;
            wsum = fmaf(g[j], D4c[0] * feat, wsum);
        }
        z = wsum;
        o0.x = wsum * v0a.x;
        o0.y = wsum * v0a.y;
        o0.z = wsum * v0a.z;
        o0.w = wsum * v0a.w;
        o1.x = wsum * v0b.x;
        o1.y = wsum * v0b.y;
        o1.z = wsum * v0b.z;
        o1.w = wsum * v0b.w;
    }  // v0 regs die here

    // ---- distinct nonzero offsets (each used by 1-2 taps, sharing k/v rows)
#pragma unroll
    for (int t = 0; t < 21; t++) {
        const int off = OFFS[t];
        if (off > nbase + 7) {
            // whole wave padded: dv == 0 exactly -> only z accumulates
            {
                const int j = U1J[t], tau = U1T[t];
                const float xx = pos_bias[(j * 4 + tau) * PH + h];
                const float feat = (xx > 0.f ? xx : __expf(xx) - 1.f) + 1.f;
                z = fmaf(g[j] * fabsf(D4c[tau]), feat, z);
            }
            if (U2J[t] >= 0) {
                const int j = U2J[t];
                const float xx = pos_bias[(j * 4 + 1) * PH + h];
                const float feat = (xx > 0.f ? xx : __expf(xx) - 1.f) + 1.f;
                z = fmaf(g[j] * D4c[1], feat, z);
            }
        } else {
            const bool valid = (n >= off);
            const int idx = valid ? (n - off) : 0;
            const float vm = valid ? 1.f : 0.f;
            const size_t rb = (base_bn + idx) * (3 * PD);
            float4 k4a, k4b;
            if (off <= 32) {
                // LDS path: lidx = (n - off) - (nblk - 32) in [0,63];
                // zero-filled rows give dot == 0 exactly for padded positions.
                const float* kl =
                    k_lds + ((n & 31) + 32 - off) * KL_STRIDE + l * 8;
                k4a = *(const float4*)kl;
                k4b = *(const float4*)(kl + 4);
            } else {
                const float* kp = qkv + rb + PD + col;
                k4a = *(const float4*)kp;
                k4b = *(const float4*)(kp + 4);
            }
            const float* vp = qkv + rb + 2 * PD + col;
            const float4 v4a = *(const float4*)vp;
            const float4 v4b = *(const float4*)(vp + 4);
            const float dv = dot8(qa, qb, k4a, k4b) * vm;

            // user 1: (U1J[t], U1T[t])
            float wv, zacc;
            {
                const int j = U1J[t], tau = U1T[t];
                const float xx = dv + pos_bias[(j * 4 + tau) * PH + h];
                const float feat = (xx > 0.f ? xx : __expf(xx) - 1.f) + 1.f;
                const float wp = g[j] * (D4c[tau] * feat);
                zacc = fabsf(wp);  // = g * |coef| * feat  (g,feat >= 0)
                wv = wp;
            }
            // user 2: (U2J[t], tau=1) if present
            if (U2J[t] >= 0) {
                const int j = U2J[t];
                const float xx = dv + pos_bias[(j * 4 + 1) * PH + h];
                const float feat = (xx > 0.f ? xx : __expf(xx) - 1.f) + 1.f;
                const float wp = g[j] * (D4c[1] * feat);
                zacc += wp;  // coef > 0
                wv += wp;
            }
            z += zacc;
            wv *= vm;
            o0.x = fmaf(wv, v4a.x, o0.x);
            o0.y = fmaf(wv, v4a.y, o0.y);
            o0.z = fmaf(wv, v4a.z, o0.z);
            o0.w = fmaf(wv, v4a.w, o0.w);
            o1.x = fmaf(wv, v4b.x, o1.x);
            o1.y = fmaf(wv, v4b.y, o1.y);
            o1.z = fmaf(wv, v4b.z, o1.z);
            o1.w = fmaf(wv, v4b.w, o1.w);
        }
    }

    // ---- tail: normalize, gate (sigmoid of bf16 logit), emit bf16
    const short8 gv = *(const short8*)(gate + (base_bn + n) * PD + col);
    const float zi = 1.f / (z + 1e-6f);

    auto sig = [](short u) {
        const float x =
            __bfloat162float(__builtin_bit_cast(__hip_bfloat16, (unsigned short)u));
        return 1.f / (1.f + __expf(-x));
    };

    short8 r;
    r[0] = (short)bf16bits(o0.x * zi * sig(gv[0]));
    r[1] = (short)bf16bits(o0.y * zi * sig(gv[1]));
    r[2] = (short)bf16bits(o0.z * zi * sig(gv[2]));
    r[3] = (short)bf16bits(o0.w * zi * sig(gv[3]));
    r[4] = (short)bf16bits(o1.x * zi * sig(gv[4]));
    r[5] = (short)bf16bits(o1.y * zi * sig(gv[5]));
    r[6] = (short)bf16bits(o1.z * zi * sig(gv[6]));
    r[7] = (short)bf16bits(o1.w * zi * sig(gv[7]));
    *(short8*)(gated + (base_bn + n) * PD + col) = r;
}

// ---------------- launch ----------------
extern "C" void kernel_launch(void* const* d_in, const int* in_sizes, int n_in,
                              void* d_out, int out_size, void* d_ws, size_t ws_size,
                              hipStream_t stream) {
    const float* x = (const float*)d_in[0];
    const float* W_qkv = (const float*)d_in[1];
    const float* b_qkv = (const float*)d_in[2];
    const float* W_out = (const float*)d_in[3];
    const float* b_out = (const float*)d_in[4];
    const float* W_gate = (const float*)d_in[5];
    const float* b_gate = (const float*)d_in[6];
    const float* scale_gain = (const float*)d_in[7];
    const float* W_qscale = (const float*)d_in[8];
    const float* identity_bypass = (const float*)d_in[9];
    const float* pos_bias = (const float*)d_in[10];
    float* out = (float*)d_out;

    const int M = PB * PN;  // 8192
    char* ws = (char*)d_ws;
    size_t off = 0;
    auto alloc = [&](size_t bytes) -> void* {
        void* p = ws + off;
        off += (bytes + 255) & ~(size_t)255;
        return p;
    };
    __hip_bfloat16* x_bf = (__hip_bfloat16*)alloc((size_t)M * PD * 2);
    __hip_bfloat16* wcomb_bf = (__hip_bfloat16*)alloc((size_t)4 * PD * PD * 2);
    __hip_bfloat16* wout_bf = (__hip_bfloat16*)alloc((size_t)PD * PD * 2);
    float* qkv = (float*)alloc((size_t)M * 3 * PD * 4);
    __hip_bfloat16* gate_bf = (__hip_bfloat16*)alloc((size_t)M * PD * 2);
    // gated ALIASES x_bf: x_bf is dead after gemm1 (its only reader); attn
    // writes gated strictly later on the same stream; cast_all fully rewrites
    // x_bf at the start of every iteration. Workspace 209 -> 176 MB (probes
    // the harness memset-gap hypothesis).
    __hip_bfloat16* gated = x_bf;

    // merged casts: x -> bf16, weights -> bf16 (one dispatch)
    const int TOT4 = M * PD / 4 + 5 * PD * PD / 4;
    cast_all<<<TOT4 / 256, 256, 0, stream>>>(
        (const float4*)x, (const float4*)W_qkv, (const float4*)W_gate,
        (const float4*)W_out, (ushort4*)x_bf, (ushort4*)wcomb_bf,
        (ushort4*)wout_bf);

    // {qkv fp32, gate bf16} = x @ [W_qkv; W_gate]^T + {b_qkv, b_gate}
    gemm_bt256<<<dim3(4 * PD / TBN, M / TBM), 512, 0, stream>>>(
        x_bf, wcomb_bf, b_qkv, b_gate, 3 * PD, qkv, 3 * PD, gate_bf, PD, PD);

    // attention + gate + bf16 emit -> gated [8192,1024] bf16
    attn_kernel<<<(PB * PH * PN) / 32, 256, 0, stream>>>(
        qkv, scale_gain, W_qscale, identity_bypass, pos_bias, gate_bf, gated);

    // out = gated @ W_out^T + b_out  (256x128 ring, 256 blocks = 1/CU, 1 round)
    gemm_bt256x128<<<dim3(PD / UBN, M / UBM), 512, 0, stream>>>(
        gated, wout_bf, b_out, out, PD, PD);
}